// Round 12
// baseline (540.815 us; speedup 1.0000x reference)
//
#include <hip/hip_runtime.h>

#define N_NODES 50000
#define N_EDGES 800000
#define IN_DIM 128
#define HID 96
#define ATTN_HID 32
#define OUT_DIM 16
#define N_SPOTS 5000
#define GN_EPS 1e-5f

#define SCAN_NB ((N_NODES + 255) / 256)   // 196
#define SCAN_SB ((N_SPOTS + 255) / 256)   // 20
#define SCB (SCAN_NB + SCAN_SB)           // 216
#define NXCD 8
#define NRANGE (N_NODES / NXCD)           // 6250
#define SRANGE (N_SPOTS / NXCD)           // 625
#define CSB 256                           // colred blocks
#define GTHB 6250                         // gather blocks

typedef short bf16x8 __attribute__((ext_vector_type(8)));
typedef float f32x4 __attribute__((ext_vector_type(4)));

// ---------------- persistent device scratch (re-initialized every call) ----
__device__ __align__(16) float g_bufA[N_NODES * HID];
__device__ __align__(16) float g_bufB[N_NODES * HID];
__device__ __align__(16) float g_bufC[N_NODES * HID];
__device__ __align__(16) float g_spot[N_SPOTS * HID];
__device__ float    g_dinv[N_NODES];      // rsqrt(deg+1)
__device__ float    g_scores[N_NODES];
__device__ int      g_deg[N_NODES];       // in-degree histogram (edges)
__device__ int      g_degs[N_SPOTS];      // spot histogram (nodes)
__device__ int      g_rp[N_NODES + 1];    // CSR row ptr (by dst)
__device__ int      g_cur[N_NODES];       // fill cursors
__device__ int      g_rps[N_SPOTS + 1];   // spot CSR row ptr
__device__ int      g_curs[N_SPOTS];
__device__ int      g_csrc[N_EDGES];      // CSR src indices
__device__ int      g_cnode[N_NODES];     // spot CSR node indices
__device__ int      g_partN[SCAN_NB];     // scan partials (RAW block totals)
__device__ int      g_partS[SCAN_SB];
__device__ float    g_gpart[GTHB][2 * HID]; // per-block stat partials (no atomics)
__device__ float    g_Spart[CSB][2 * HID];  // 2nd-level stat partials
__device__ float    g_ab[4 * 2 * HID];    // 4 GN stages x (alpha, beta)

__device__ __forceinline__ float* pick(int id) {
  switch (id) {
    case 0:  return g_bufA;
    case 1:  return g_bufB;
    case 2:  return g_bufC;
    default: return g_spot;
  }
}

__device__ __forceinline__ unsigned short bf16_rn(float f) {
  unsigned u = __float_as_uint(f);
  unsigned r = u + 0x7FFFu + ((u >> 16) & 1u);
  return (unsigned short)(r >> 16);
}

// ---------------- init: zero histograms ------------------------------------
__global__ __launch_bounds__(256) void k_init() {
  int i = blockIdx.x * 256 + threadIdx.x;
  if (i < N_NODES) g_deg[i] = 0;
  if (i < N_SPOTS) g_degs[i] = 0;
}

// ---------------- XCD-local histograms ------------------------------------
__global__ __launch_bounds__(256) void k_hist(const int* __restrict__ dst,
                                              const int* __restrict__ c2s) {
  int r = blockIdx.x & 7;
  int cb = blockIdx.x >> 3;
  int stride = (gridDim.x >> 3) * 256;
  int nlo = r * NRANGE, nhi = nlo + NRANGE;
  int slo = r * SRANGE, shi = slo + SRANGE;
  for (int i = cb * 256 + threadIdx.x; i < N_EDGES; i += stride) {
    int d = dst[i];
    if (d >= nlo && d < nhi) atomicAdd(&g_deg[d], 1);
  }
  for (int i = cb * 256 + threadIdx.x; i < N_NODES; i += stride) {
    int sp = c2s[i];
    if (sp >= slo && sp < shi) atomicAdd(&g_degs[sp], 1);
  }
}

// ---------------- scan phase 1: raw per-block totals -----------------------
__global__ __launch_bounds__(256) void k_scan1() {
  bool isS = blockIdx.x >= SCAN_NB;
  int b = isS ? blockIdx.x - SCAN_NB : blockIdx.x;
  const int n = isS ? N_SPOTS : N_NODES;
  const int* deg = isS ? g_degs : g_deg;
  int i = b * 256 + threadIdx.x;
  int v = (i < n) ? deg[i] : 0;
#pragma unroll
  for (int o = 32; o >= 1; o >>= 1) v += __shfl_xor(v, o);
  __shared__ int red[4];
  if ((threadIdx.x & 63) == 0) red[threadIdx.x >> 6] = v;
  __syncthreads();
  if (threadIdx.x == 0)
    (isS ? g_partS : g_partN)[b] = red[0] + red[1] + red[2] + red[3];
}

// ---------------- scan phase 3 with inline prefix (replaces scan2) ---------
__global__ __launch_bounds__(256) void k_scan3() {
  bool isS = blockIdx.x >= SCAN_NB;
  int b = isS ? blockIdx.x - SCAN_NB : blockIdx.x;
  const int n = isS ? N_SPOTS : N_NODES;
  const int* deg = isS ? g_degs : g_deg;
  int* rp  = isS ? g_rps  : g_rp;
  int* cur = isS ? g_curs : g_cur;
  const int* part = isS ? g_partS : g_partN;  // RAW totals
  int t = threadIdx.x;
  // base = sum part[0..b-1]
  int pv = (t < b) ? part[t] : 0;
#pragma unroll
  for (int o = 32; o >= 1; o >>= 1) pv += __shfl_xor(pv, o);
  __shared__ int red3[4];
  if ((t & 63) == 0) red3[t >> 6] = pv;
  __syncthreads();
  int base = red3[0] + red3[1] + red3[2] + red3[3];
  // local exclusive scan of this block's 256 degrees
  __shared__ int tmp[256];
  int i = b * 256 + t;
  int v = (i < n) ? deg[i] : 0;
  tmp[t] = v;
  __syncthreads();
  for (int o = 1; o < 256; o <<= 1) {
    int u = (t >= o) ? tmp[t - o] : 0;
    __syncthreads();
    tmp[t] += u;
    __syncthreads();
  }
  if (i < n) {
    int off = base + tmp[t] - v;
    rp[i] = off;
    cur[i] = off;
    if (i == n - 1) rp[n] = off + v;
    if (!isS) g_dinv[i] = rsqrtf((float)(v + 1));
  }
}

// ---------------- XCD-local CSR fill ---------------------------------------
__global__ __launch_bounds__(256) void k_fill(const int* __restrict__ src,
                                              const int* __restrict__ dst,
                                              const int* __restrict__ c2s) {
  int r = blockIdx.x & 7;
  int cb = blockIdx.x >> 3;
  int stride = (gridDim.x >> 3) * 256;
  int nlo = r * NRANGE, nhi = nlo + NRANGE;
  int slo = r * SRANGE, shi = slo + SRANGE;
  for (int i = cb * 256 + threadIdx.x; i < N_EDGES; i += stride) {
    int d = dst[i];
    if (d >= nlo && d < nhi) {
      int p = atomicAdd(&g_cur[d], 1);
      g_csrc[p] = src[i];
    }
  }
  for (int i = cb * 256 + threadIdx.x; i < N_NODES; i += stride) {
    int sp = c2s[i];
    if (sp >= slo && sp < shi) {
      int p = atomicAdd(&g_curs[sp], 1);
      g_cnode[p] = i;
    }
  }
}

// ---------------- MFMA bf16x3 GEMM: out[nrows x 96] (R10-proven) -----------
// fp32 operands split a = ah + al (bf16 RTN); D = al*bh + ah*bl + ah*bh.
// W staged+split in LDS. STATS: per-block column partials.
// A: row=l&15, k=(l>>4)*8+j; B: col=l&15; C/D: col=l&15, row=(l>>4)*4+j [m89].
template <int K, bool AFF, bool SCALE, bool STATS>
__global__ __launch_bounds__(256) void k_mfma(const float* __restrict__ Aext,
                                              int a_id, int out_id,
                                              const float* __restrict__ W,
                                              const float* __restrict__ bias,
                                              int stage, int nrows) {
  constexpr int CH = K / 32;
  __shared__ unsigned short WF[CH][6][64][8];   // hi fragments
  __shared__ unsigned short WL[CH][6][64][8];   // lo fragments
  __shared__ float abs_[2 * HID];
  __shared__ float bs[HID];
  const float* A = Aext ? Aext : pick(a_id);
  float* out = pick(out_id);
  int tid = threadIdx.x;
  if (AFF && tid < 2 * HID) abs_[tid] = g_ab[stage * 2 * HID + tid];
  if (tid < HID) bs[tid] = bias ? bias[tid] : 0.f;
  for (int idx = tid; idx < CH * 6 * 64; idx += 256) {
    int lane = idx & 63;
    int ct = (idx >> 6) % 6;
    int ch = idx / (6 * 64);
    int kbase = ch * 32 + (lane >> 4) * 8;
    int c = ct * 16 + (lane & 15);
#pragma unroll
    for (int j = 0; j < 8; ++j) {
      float w = W[(size_t)(kbase + j) * HID + c];
      unsigned short h = bf16_rn(w);
      WF[ch][ct][lane][j] = h;
      WL[ch][ct][lane][j] = bf16_rn(w - __uint_as_float((unsigned)h << 16));
    }
  }
  __syncthreads();

  int wv = tid >> 6, lane = tid & 63;
  int r0 = blockIdx.x * 64 + wv * 16;
  int arow = r0 + (lane & 15);
  f32x4 acc[6];
#pragma unroll
  for (int t = 0; t < 6; ++t) acc[t] = (f32x4){0.f, 0.f, 0.f, 0.f};

  for (int ch = 0; ch < CH; ++ch) {
    int ks = ch * 32 + (lane >> 4) * 8;
    float av[8];
    if (arow < nrows) {
      const float4* ap = reinterpret_cast<const float4*>(A + (size_t)arow * K + ks);
      float4 v0 = ap[0], v1 = ap[1];
      av[0] = v0.x; av[1] = v0.y; av[2] = v0.z; av[3] = v0.w;
      av[4] = v1.x; av[5] = v1.y; av[6] = v1.z; av[7] = v1.w;
    } else {
#pragma unroll
      for (int j = 0; j < 8; ++j) av[j] = 0.f;
    }
    if (AFF) {
#pragma unroll
      for (int j = 0; j < 8; ++j)
        av[j] = fmaxf(av[j] * abs_[ks + j] + abs_[HID + ks + j], 0.f);
    }
    bf16x8 ah, al;
#pragma unroll
    for (int j = 0; j < 8; ++j) {
      unsigned short h = bf16_rn(av[j]);
      ah[j] = (short)h;
      al[j] = (short)bf16_rn(av[j] - __uint_as_float((unsigned)h << 16));
    }
#pragma unroll
    for (int ct = 0; ct < 6; ++ct) {
      bf16x8 bh = *reinterpret_cast<const bf16x8*>(&WF[ch][ct][lane][0]);
      bf16x8 bl = *reinterpret_cast<const bf16x8*>(&WL[ch][ct][lane][0]);
      acc[ct] = __builtin_amdgcn_mfma_f32_16x16x32_bf16(al, bh, acc[ct], 0, 0, 0);
      acc[ct] = __builtin_amdgcn_mfma_f32_16x16x32_bf16(ah, bl, acc[ct], 0, 0, 0);
      acc[ct] = __builtin_amdgcn_mfma_f32_16x16x32_bf16(ah, bh, acc[ct], 0, 0, 0);
    }
  }
  int rbase = r0 + (lane >> 4) * 4;
  float dv[4];
#pragma unroll
  for (int j = 0; j < 4; ++j) {
    int r = rbase + j;
    dv[j] = SCALE ? ((r < nrows) ? g_dinv[r] : 0.f) : 1.f;
  }
  float s1[6], s2[6];
#pragma unroll
  for (int ct = 0; ct < 6; ++ct) { s1[ct] = 0.f; s2[ct] = 0.f; }
#pragma unroll
  for (int ct = 0; ct < 6; ++ct) {
    int col = ct * 16 + (lane & 15);
    float bb = bs[col];
#pragma unroll
    for (int j = 0; j < 4; ++j) {
      int r = rbase + j;
      if (r < nrows) {
        float v = acc[ct][j] * dv[j] + bb;
        out[(size_t)r * HID + col] = v;
        if (STATS) { s1[ct] += v; s2[ct] += v * v; }
      }
    }
  }
  if constexpr (STATS) {
#pragma unroll
    for (int o = 16; o <= 32; o <<= 1) {
#pragma unroll
      for (int ct = 0; ct < 6; ++ct) {
        s1[ct] += __shfl_xor(s1[ct], o);
        s2[ct] += __shfl_xor(s2[ct], o);
      }
    }
    __shared__ float sr1[4][6][16], sr2[4][6][16];
    if (lane < 16) {
#pragma unroll
      for (int ct = 0; ct < 6; ++ct) {
        sr1[wv][ct][lane] = s1[ct];
        sr2[wv][ct][lane] = s2[ct];
      }
    }
    __syncthreads();
    if (tid < 2 * HID) {
      int c = (tid < HID) ? tid : tid - HID;
      int ct = c >> 4, l = c & 15;
      float s = 0.f;
#pragma unroll
      for (int w = 0; w < 4; ++w)
        s += (tid < HID) ? sr1[w][ct][l] : sr2[w][ct][l];
      g_gpart[blockIdx.x][tid] = s;
    }
  }
}

// ---------------- vector GEMM (MLP head) + stats partials ------------------
template <int K, bool AFF, bool SCALE, bool STATS>
__global__ __launch_bounds__(256) void k_gemm96(const float* __restrict__ Aext,
                                                int a_id, int out_id,
                                                const float* __restrict__ W,
                                                const float* __restrict__ bias,
                                                int stage, int nrows) {
  constexpr int KC = 32;
  constexpr int ROWS = 64;
  __shared__ __align__(16) float Ws[KC][HID];
  __shared__ float xs[ROWS][KC + 1];
  __shared__ float abs_[2 * HID];
  const float* A = Aext ? Aext : pick(a_id);
  float* out = pick(out_id);
  int tid = threadIdx.x;
  if (AFF && tid < 2 * HID) abs_[tid] = g_ab[stage * 2 * HID + tid];
  int r0 = blockIdx.x * ROWS;
  int rg = tid >> 3;
  int cg = (tid & 7) * 12;
  float acc[2][12];
#pragma unroll
  for (int i = 0; i < 2; ++i)
#pragma unroll
    for (int c = 0; c < 12; ++c) acc[i][c] = 0.f;

  for (int k0 = 0; k0 < K; k0 += KC) {
    __syncthreads();
    for (int f = tid; f < KC * HID / 4; f += 256) {
      reinterpret_cast<float4*>(&Ws[0][0])[f] =
          reinterpret_cast<const float4*>(W + (size_t)k0 * HID)[f];
    }
    for (int f = tid; f < ROWS * KC / 4; f += 256) {
      int r = f >> 3;
      int kk = (f & 7) << 2;
      int row = r0 + r;
      float4 v = make_float4(0.f, 0.f, 0.f, 0.f);
      if (row < nrows)
        v = *reinterpret_cast<const float4*>(A + (size_t)row * K + k0 + kk);
      if (AFF) {
        int c = k0 + kk;
        v.x = fmaxf(v.x * abs_[c]     + abs_[HID + c],     0.f);
        v.y = fmaxf(v.y * abs_[c + 1] + abs_[HID + c + 1], 0.f);
        v.z = fmaxf(v.z * abs_[c + 2] + abs_[HID + c + 2], 0.f);
        v.w = fmaxf(v.w * abs_[c + 3] + abs_[HID + c + 3], 0.f);
      }
      xs[r][kk] = v.x; xs[r][kk + 1] = v.y; xs[r][kk + 2] = v.z; xs[r][kk + 3] = v.w;
    }
    __syncthreads();
#pragma unroll
    for (int k = 0; k < KC; ++k) {
      float x0 = xs[rg][k];
      float x1 = xs[rg + 32][k];
#pragma unroll
      for (int c = 0; c < 12; ++c) {
        float wv = Ws[k][cg + c];
        acc[0][c] += x0 * wv;
        acc[1][c] += x1 * wv;
      }
    }
  }
  float s1[12], s2[12];
#pragma unroll
  for (int c = 0; c < 12; ++c) { s1[c] = 0.f; s2[c] = 0.f; }
#pragma unroll
  for (int i = 0; i < 2; ++i) {
    int row = r0 + rg + 32 * i;
    if (row < nrows) {
      float sc = SCALE ? g_dinv[row] : 1.f;
#pragma unroll
      for (int c = 0; c < 12; ++c) {
        float v = acc[i][c] * sc;
        if (bias) v += bias[cg + c];
        out[(size_t)row * HID + cg + c] = v;
        if (STATS) { s1[c] += v; s2[c] += v * v; }
      }
    }
  }
  if constexpr (STATS) {
#pragma unroll
    for (int off = 8; off <= 32; off <<= 1) {
#pragma unroll
      for (int c = 0; c < 12; ++c) {
        s1[c] += __shfl_xor(s1[c], off);
        s2[c] += __shfl_xor(s2[c], off);
      }
    }
    __shared__ float sred[4][8][24];
    int wv = tid >> 6, ln = tid & 63;
    if (ln < 8) {
#pragma unroll
      for (int c = 0; c < 12; ++c) {
        sred[wv][ln][2 * c] = s1[c];
        sred[wv][ln][2 * c + 1] = s2[c];
      }
    }
    __syncthreads();
    if (tid < 192) {
      int cg2 = tid / 24, j = tid % 24;
      float s = sred[0][cg2][j] + sred[1][cg2][j] + sred[2][cg2][j] + sred[3][cg2][j];
      int col = cg2 * 12 + (j >> 1);
      g_gpart[blockIdx.x][(j & 1) ? HID + col : col] = s;
    }
  }
}

// ---------------- GCN aggregation via CSR gather (+ block stat partials) ----
__global__ __launch_bounds__(256) void k_gather(int t_id, const float* __restrict__ b,
                                                int agg_id) {
  const float* __restrict__ t = pick(t_id);
  float* __restrict__ agg = pick(agg_id);
  int g = (blockIdx.x * 256 + threadIdx.x) >> 5;
  int lane = threadIdx.x & 31;
  int beg = g_rp[g], end = g_rp[g + 1];
  const float* __restrict__ tg = t + (size_t)g * HID;
  float a0 = tg[lane], a1 = tg[32 + lane], a2 = tg[64 + lane];
  int e = beg;
  for (; e + 8 <= end; e += 8) {
    const float* p0 = t + (size_t)g_csrc[e]     * HID;
    const float* p1 = t + (size_t)g_csrc[e + 1] * HID;
    const float* p2 = t + (size_t)g_csrc[e + 2] * HID;
    const float* p3 = t + (size_t)g_csrc[e + 3] * HID;
    const float* p4 = t + (size_t)g_csrc[e + 4] * HID;
    const float* p5 = t + (size_t)g_csrc[e + 5] * HID;
    const float* p6 = t + (size_t)g_csrc[e + 6] * HID;
    const float* p7 = t + (size_t)g_csrc[e + 7] * HID;
    a0 += p0[lane]; a1 += p0[32 + lane]; a2 += p0[64 + lane];
    a0 += p1[lane]; a1 += p1[32 + lane]; a2 += p1[64 + lane];
    a0 += p2[lane]; a1 += p2[32 + lane]; a2 += p2[64 + lane];
    a0 += p3[lane]; a1 += p3[32 + lane]; a2 += p3[64 + lane];
    a0 += p4[lane]; a1 += p4[32 + lane]; a2 += p4[64 + lane];
    a0 += p5[lane]; a1 += p5[32 + lane]; a2 += p5[64 + lane];
    a0 += p6[lane]; a1 += p6[32 + lane]; a2 += p6[64 + lane];
    a0 += p7[lane]; a1 += p7[32 + lane]; a2 += p7[64 + lane];
  }
  for (; e < end; ++e) {
    const float* __restrict__ ts = t + (size_t)g_csrc[e] * HID;
    a0 += ts[lane]; a1 += ts[32 + lane]; a2 += ts[64 + lane];
  }
  float di = g_dinv[g];
  float v0 = di * a0 + b[lane];
  float v1 = di * a1 + b[32 + lane];
  float v2 = di * a2 + b[64 + lane];
  size_t o = (size_t)g * HID;
  agg[o + lane]      = v0;
  agg[o + 32 + lane] = v1;
  agg[o + 64 + lane] = v2;
  float q0 = v0, q1 = v1, q2 = v2;
  float r0s = v0 * v0, r1s = v1 * v1, r2s = v2 * v2;
  q0 += __shfl_xor(q0, 32); r0s += __shfl_xor(r0s, 32);
  q1 += __shfl_xor(q1, 32); r1s += __shfl_xor(r1s, 32);
  q2 += __shfl_xor(q2, 32); r2s += __shfl_xor(r2s, 32);
  __shared__ float sred[4][32][6];
  int wv = threadIdx.x >> 6, ln = threadIdx.x & 63;
  if (ln < 32) {
    sred[wv][ln][0] = q0;  sred[wv][ln][1] = r0s;
    sred[wv][ln][2] = q1;  sred[wv][ln][3] = r1s;
    sred[wv][ln][4] = q2;  sred[wv][ln][5] = r2s;
  }
  __syncthreads();
  if (threadIdx.x < 192) {
    int l2 = threadIdx.x / 6, j = threadIdx.x % 6;
    float s = sred[0][l2][j] + sred[1][l2][j] + sred[2][l2][j] + sred[3][l2][j];
    int dim = l2 + (j >> 1) * 32;
    g_gpart[blockIdx.x][(j & 1) ? HID + dim : dim] = s;
  }
}

// ---------------- colred: reduce g_gpart[count] -> g_Spart[CSB] ------------
__global__ __launch_bounds__(256) void k_colred(int count) {
  int tid = threadIdx.x;
  if (tid >= 2 * HID) return;
  float s = 0.f;
  for (int k = blockIdx.x; k < count; k += gridDim.x) s += g_gpart[k][tid];
  g_Spart[blockIdx.x][tid] = s;
}

// ---------------- gnreduce: sum partial rows + compute alpha/beta ----------
__global__ __launch_bounds__(256) void k_gnreduce(int stage, const float* __restrict__ w,
                                                  const float* __restrict__ b,
                                                  const float* __restrict__ a,
                                                  float invn, int fromGpart, int count) {
  const float (*__restrict__ arr)[2 * HID] = fromGpart ? g_gpart : g_Spart;
  __shared__ float S[2 * HID];
  int tid = threadIdx.x;
  if (tid < 2 * HID) {
    float s = 0.f;
    for (int k = 0; k < count; ++k) s += arr[k][tid];
    S[tid] = s;
  }
  __syncthreads();
  if (tid < HID) {
    float mean = S[tid] * invn;
    float var = S[HID + tid] * invn + mean * mean * (a[tid] * a[tid] - 2.f * a[tid]);
    float r = rsqrtf(var + GN_EPS);
    float alpha = w[tid] * r;
    g_ab[stage * 2 * HID + tid] = alpha;
    g_ab[stage * 2 * HID + HID + tid] = b[tid] - alpha * a[tid] * mean;
  }
}

// ---------------- attention scores (fused GN affine on input) --------------
__global__ __launch_bounds__(256) void k_scores(int h_id, int stage,
                                                const float* __restrict__ W1,
                                                const float* __restrict__ b1,
                                                const float* __restrict__ W2,
                                                const float* __restrict__ b2) {
  __shared__ float W1s[HID * ATTN_HID];
  __shared__ float b1s[ATTN_HID], W2s[ATTN_HID];
  __shared__ float abs_[2 * HID];
  const float* h = pick(h_id);
  const float* ab = g_ab + stage * 2 * HID;
  int tid = threadIdx.x;
  for (int f = tid; f < HID * ATTN_HID; f += 256) W1s[f] = W1[f];
  if (tid < ATTN_HID) { b1s[tid] = b1[tid]; W2s[tid] = W2[tid]; }
  if (tid < 2 * HID) abs_[tid] = ab[tid];
  __syncthreads();
  int i = blockIdx.x * 256 + tid;
  if (i >= N_NODES) return;
  float acc[ATTN_HID];
#pragma unroll
  for (int k = 0; k < ATTN_HID; ++k) acc[k] = 0.f;
  const float4* h4 = reinterpret_cast<const float4*>(h + (size_t)i * HID);
  for (int j4 = 0; j4 < HID / 4; ++j4) {
    float4 hv4 = h4[j4];
    int j = j4 * 4;
    float h0 = fmaxf(hv4.x * abs_[j]     + abs_[HID + j],     0.f);
    float h1 = fmaxf(hv4.y * abs_[j + 1] + abs_[HID + j + 1], 0.f);
    float h2 = fmaxf(hv4.z * abs_[j + 2] + abs_[HID + j + 2], 0.f);
    float h3 = fmaxf(hv4.w * abs_[j + 3] + abs_[HID + j + 3], 0.f);
#pragma unroll
    for (int k = 0; k < ATTN_HID; ++k) {
      acc[k] += h0 * W1s[j * ATTN_HID + k] + h1 * W1s[(j + 1) * ATTN_HID + k] +
                h2 * W1s[(j + 2) * ATTN_HID + k] + h3 * W1s[(j + 3) * ATTN_HID + k];
    }
  }
  float s = b2[0];
#pragma unroll
  for (int k = 0; k < ATTN_HID; ++k) s += fmaxf(acc[k] + b1s[k], 0.f) * W2s[k];
  g_scores[i] = s;
}

// ---------------- segment softmax + weighted aggregation (CSR, no atomics) -
__global__ __launch_bounds__(256) void k_spotagg(int h_id, int stage) {
  const float* __restrict__ h = pick(h_id);
  const float* ab = g_ab + stage * 2 * HID;
  int g = (blockIdx.x * 256 + threadIdx.x) >> 5;
  int lane = threadIdx.x & 31;
  if (g >= N_SPOTS) return;
  int beg = g_rps[g], end = g_rps[g + 1];
  float m = -1e30f;
  for (int i = beg + lane; i < end; i += 32) m = fmaxf(m, g_scores[g_cnode[i]]);
#pragma unroll
  for (int o = 16; o >= 1; o >>= 1) m = fmaxf(m, __shfl_xor(m, o, 32));
  float al0 = ab[lane],      be0 = ab[HID + lane];
  float al1 = ab[32 + lane], be1 = ab[HID + 32 + lane];
  float al2 = ab[64 + lane], be2 = ab[HID + 64 + lane];
  float a0 = 0.f, a1 = 0.f, a2 = 0.f, denom = 0.f;
  for (int i = beg; i < end; ++i) {
    int nd = g_cnode[i];
    float e = __expf(g_scores[nd] - m);
    denom += e;
    const float* __restrict__ hr = h + (size_t)nd * HID;
    a0 += e * fmaxf(hr[lane] * al0 + be0, 0.f);
    a1 += e * fmaxf(hr[32 + lane] * al1 + be1, 0.f);
    a2 += e * fmaxf(hr[64 + lane] * al2 + be2, 0.f);
  }
  float inv = (denom > 0.f) ? 1.f / denom : 0.f;
  g_spot[g * HID + lane]      = a0 * inv;
  g_spot[g * HID + 32 + lane] = a1 * inv;
  g_spot[g * HID + 64 + lane] = a2 * inv;
}

// ---------------- final: out = relu(gn(t3)) @ mlp_W2 + b2 ------------------
__global__ __launch_bounds__(256) void k_final(int t3_id, int stage,
                                               const float* __restrict__ W2,
                                               const float* __restrict__ b2,
                                               float* __restrict__ out) {
  __shared__ float W2s[HID * OUT_DIM];
  const float* t3 = pick(t3_id);
  const float* ab = g_ab + stage * 2 * HID;
  int tid = threadIdx.x;
  for (int f = tid; f < HID * OUT_DIM; f += 256) W2s[f] = W2[f];
  __syncthreads();
  int r = blockIdx.x * 16 + (tid >> 4);
  int c = tid & 15;
  if (r >= N_SPOTS) return;
  float acc = b2[c];
  for (int j = 0; j < HID; ++j) {
    float z = fmaxf(t3[(size_t)r * HID + j] * ab[j] + ab[HID + j], 0.f);
    acc += z * W2s[j * OUT_DIM + c];
  }
  out[r * OUT_DIM + c] = acc;
}

// ---------------------------------------------------------------------------
extern "C" void kernel_launch(void* const* d_in, const int* in_sizes, int n_in,
                              void* d_out, int out_size, void* d_ws, size_t ws_size,
                              hipStream_t stream) {
  const float* x       = (const float*)d_in[0];
  const int*   ei      = (const int*)d_in[1];
  const int*   src     = ei;
  const int*   dst     = ei + N_EDGES;
  const int*   c2s     = (const int*)d_in[2];
  const float* proj_W  = (const float*)d_in[4];
  const float* proj_b  = (const float*)d_in[5];
  const float* gn0_w   = (const float*)d_in[6];
  const float* gn0_b   = (const float*)d_in[7];
  const float* gn0_a   = (const float*)d_in[8];
  const float* gcn1_W  = (const float*)d_in[9];
  const float* gcn1_b  = (const float*)d_in[10];
  const float* gn1_w   = (const float*)d_in[11];
  const float* gn1_b   = (const float*)d_in[12];
  const float* gn1_a   = (const float*)d_in[13];
  const float* gcn2_W  = (const float*)d_in[14];
  const float* gcn2_b  = (const float*)d_in[15];
  const float* gn2_w   = (const float*)d_in[16];
  const float* gn2_b   = (const float*)d_in[17];
  const float* gn2_a   = (const float*)d_in[18];
  const float* attn_W1 = (const float*)d_in[19];
  const float* attn_b1 = (const float*)d_in[20];
  const float* attn_W2 = (const float*)d_in[21];
  const float* attn_b2 = (const float*)d_in[22];
  const float* mlp_W1  = (const float*)d_in[23];
  const float* mlp_b1  = (const float*)d_in[24];
  const float* mlp_gn_w = (const float*)d_in[25];
  const float* mlp_gn_b = (const float*)d_in[26];
  const float* mlp_gn_a = (const float*)d_in[27];
  const float* mlp_W2  = (const float*)d_in[28];
  const float* mlp_b2  = (const float*)d_in[29];
  float* out = (float*)d_out;

  const float invN = 1.f / (float)N_NODES;
  const float invS = 1.f / (float)N_SPOTS;
  const int MFB  = (N_NODES + 63) / 64;     // 782
  const int GB_S = (N_SPOTS + 63) / 64;     // 79
  const int XB   = NXCD * 96;               // 768
  const int SPB  = (N_SPOTS * 32 + 255) / 256;

  // ---- CSR build ----
  k_init<<<(N_NODES + 255) / 256, 256, 0, stream>>>();
  k_hist<<<XB, 256, 0, stream>>>(dst, c2s);
  k_scan1<<<SCB, 256, 0, stream>>>();
  k_scan3<<<SCB, 256, 0, stream>>>();   // inline prefix replaces scan2
  k_fill<<<XB, 256, 0, stream>>>(src, dst, c2s);

  // ---- stage 0: proj (MFMA bf16x3, stats fused into epilogue) ----
  k_mfma<IN_DIM, false, false, true><<<MFB, 256, 0, stream>>>(x, -1, 0, proj_W, proj_b, 0, N_NODES);
  k_colred<<<CSB, 256, 0, stream>>>(MFB);
  k_gnreduce<<<1, 256, 0, stream>>>(0, gn0_w, gn0_b, gn0_a, invN, 0, CSB);

  // ---- GCN layer 1 ----
  k_mfma<HID, true, true, false><<<MFB, 256, 0, stream>>>(nullptr, 0, 1, gcn1_W, nullptr, 0, N_NODES);
  k_gather<<<GTHB, 256, 0, stream>>>(1, gcn1_b, 0);
  k_colred<<<CSB, 256, 0, stream>>>(GTHB);
  k_gnreduce<<<1, 256, 0, stream>>>(1, gn1_w, gn1_b, gn1_a, invN, 0, CSB);

  // ---- GCN layer 2 ----
  k_mfma<HID, true, true, false><<<MFB, 256, 0, stream>>>(nullptr, 0, 2, gcn2_W, nullptr, 1, N_NODES);
  k_gather<<<GTHB, 256, 0, stream>>>(2, gcn2_b, 1);
  k_colred<<<CSB, 256, 0, stream>>>(GTHB);
  k_gnreduce<<<1, 256, 0, stream>>>(2, gn2_w, gn2_b, gn2_a, invN, 0, CSB);

  // ---- attention + segment softmax + spot aggregation ----
  k_scores<<<(N_NODES + 255) / 256, 256, 0, stream>>>(1, 2, attn_W1, attn_b1, attn_W2, attn_b2);
  k_spotagg<<<SPB, 256, 0, stream>>>(1, 2);

  // ---- MLP head (stats fused; gnreduce reads g_gpart directly) ----
  k_gemm96<HID, false, false, true><<<GB_S, 256, 0, stream>>>(nullptr, 3, 2, mlp_W1, mlp_b1, 0, N_SPOTS);
  k_gnreduce<<<1, 256, 0, stream>>>(3, mlp_gn_w, mlp_gn_b, mlp_gn_a, invS, 1, GB_S);
  k_final<<<(N_SPOTS + 15) / 16, 256, 0, stream>>>(2, 3, mlp_W2, mlp_b2, out);
}

// Round 13
// 357.499 us; speedup vs baseline: 1.5128x; 1.5128x over previous
//
#include <hip/hip_runtime.h>

#define N_NODES 50000
#define N_EDGES 800000
#define IN_DIM 128
#define HID 96
#define ATTN_HID 32
#define OUT_DIM 16
#define N_SPOTS 5000
#define GN_EPS 1e-5f

#define SCAN_NB ((N_NODES + 255) / 256)   // 196
#define SCAN_SB ((N_SPOTS + 255) / 256)   // 20
#define SCB (SCAN_NB + SCAN_SB)           // 216
#define NXCD 8
#define NRANGE (N_NODES / NXCD)           // 6250
#define SRANGE (N_SPOTS / NXCD)           // 625
#define CSB 256                           // colred blocks
#define GTHB 6250                         // gather blocks

typedef short bf16x8 __attribute__((ext_vector_type(8)));
typedef float f32x4 __attribute__((ext_vector_type(4)));

// ---------------- persistent device scratch (re-initialized every call) ----
__device__ __align__(16) float g_bufA[N_NODES * HID];
__device__ __align__(16) float g_bufB[N_NODES * HID];
__device__ __align__(16) float g_bufC[N_NODES * HID];
__device__ __align__(16) float g_spot[N_SPOTS * HID];
__device__ float    g_dinv[N_NODES];      // rsqrt(deg+1)
__device__ float    g_scores[N_NODES];
__device__ int      g_deg[N_NODES];       // in-degree histogram (edges)
__device__ int      g_degs[N_SPOTS];      // spot histogram (nodes)
__device__ int      g_rp[N_NODES + 1];    // CSR row ptr (by dst)
__device__ int      g_cur[N_NODES];       // fill cursors
__device__ int      g_rps[N_SPOTS + 1];   // spot CSR row ptr
__device__ int      g_curs[N_SPOTS];
__device__ int      g_csrc[N_EDGES];      // CSR src indices
__device__ int      g_cnode[N_NODES];     // spot CSR node indices
__device__ int      g_partN[SCAN_NB];     // scan partials (RAW block totals)
__device__ int      g_partS[SCAN_SB];
__device__ float    g_gpart[GTHB][2 * HID]; // per-block stat partials (no atomics)
__device__ float    g_Spart[CSB][2 * HID];  // 2nd-level stat partials
__device__ float    g_ab[4 * 2 * HID];    // 4 GN stages x (alpha, beta)

__device__ __forceinline__ float* pick(int id) {
  switch (id) {
    case 0:  return g_bufA;
    case 1:  return g_bufB;
    case 2:  return g_bufC;
    default: return g_spot;
  }
}

__device__ __forceinline__ unsigned short bf16_rn(float f) {
  unsigned u = __float_as_uint(f);
  unsigned r = u + 0x7FFFu + ((u >> 16) & 1u);
  return (unsigned short)(r >> 16);
}

// ---------------- init: zero histograms ------------------------------------
__global__ __launch_bounds__(256) void k_init() {
  int i = blockIdx.x * 256 + threadIdx.x;
  if (i < N_NODES) g_deg[i] = 0;
  if (i < N_SPOTS) g_degs[i] = 0;
}

// ---------------- XCD-local histograms ------------------------------------
__global__ __launch_bounds__(256) void k_hist(const int* __restrict__ dst,
                                              const int* __restrict__ c2s) {
  int r = blockIdx.x & 7;
  int cb = blockIdx.x >> 3;
  int stride = (gridDim.x >> 3) * 256;
  int nlo = r * NRANGE, nhi = nlo + NRANGE;
  int slo = r * SRANGE, shi = slo + SRANGE;
  for (int i = cb * 256 + threadIdx.x; i < N_EDGES; i += stride) {
    int d = dst[i];
    if (d >= nlo && d < nhi) atomicAdd(&g_deg[d], 1);
  }
  for (int i = cb * 256 + threadIdx.x; i < N_NODES; i += stride) {
    int sp = c2s[i];
    if (sp >= slo && sp < shi) atomicAdd(&g_degs[sp], 1);
  }
}

// ---------------- scan phase 1: raw per-block totals -----------------------
__global__ __launch_bounds__(256) void k_scan1() {
  bool isS = blockIdx.x >= SCAN_NB;
  int b = isS ? blockIdx.x - SCAN_NB : blockIdx.x;
  const int n = isS ? N_SPOTS : N_NODES;
  const int* deg = isS ? g_degs : g_deg;
  int i = b * 256 + threadIdx.x;
  int v = (i < n) ? deg[i] : 0;
#pragma unroll
  for (int o = 32; o >= 1; o >>= 1) v += __shfl_xor(v, o);
  __shared__ int red[4];
  if ((threadIdx.x & 63) == 0) red[threadIdx.x >> 6] = v;
  __syncthreads();
  if (threadIdx.x == 0)
    (isS ? g_partS : g_partN)[b] = red[0] + red[1] + red[2] + red[3];
}

// ---------------- scan phase 3 with inline prefix (replaces scan2) ---------
__global__ __launch_bounds__(256) void k_scan3() {
  bool isS = blockIdx.x >= SCAN_NB;
  int b = isS ? blockIdx.x - SCAN_NB : blockIdx.x;
  const int n = isS ? N_SPOTS : N_NODES;
  const int* deg = isS ? g_degs : g_deg;
  int* rp  = isS ? g_rps  : g_rp;
  int* cur = isS ? g_curs : g_cur;
  const int* part = isS ? g_partS : g_partN;  // RAW totals
  int t = threadIdx.x;
  // base = sum part[0..b-1]
  int pv = (t < b) ? part[t] : 0;
#pragma unroll
  for (int o = 32; o >= 1; o >>= 1) pv += __shfl_xor(pv, o);
  __shared__ int red3[4];
  if ((t & 63) == 0) red3[t >> 6] = pv;
  __syncthreads();
  int base = red3[0] + red3[1] + red3[2] + red3[3];
  // local exclusive scan of this block's 256 degrees
  __shared__ int tmp[256];
  int i = b * 256 + t;
  int v = (i < n) ? deg[i] : 0;
  tmp[t] = v;
  __syncthreads();
  for (int o = 1; o < 256; o <<= 1) {
    int u = (t >= o) ? tmp[t - o] : 0;
    __syncthreads();
    tmp[t] += u;
    __syncthreads();
  }
  if (i < n) {
    int off = base + tmp[t] - v;
    rp[i] = off;
    cur[i] = off;
    if (i == n - 1) rp[n] = off + v;
    if (!isS) g_dinv[i] = rsqrtf((float)(v + 1));
  }
}

// ---------------- XCD-local CSR fill ---------------------------------------
__global__ __launch_bounds__(256) void k_fill(const int* __restrict__ src,
                                              const int* __restrict__ dst,
                                              const int* __restrict__ c2s) {
  int r = blockIdx.x & 7;
  int cb = blockIdx.x >> 3;
  int stride = (gridDim.x >> 3) * 256;
  int nlo = r * NRANGE, nhi = nlo + NRANGE;
  int slo = r * SRANGE, shi = slo + SRANGE;
  for (int i = cb * 256 + threadIdx.x; i < N_EDGES; i += stride) {
    int d = dst[i];
    if (d >= nlo && d < nhi) {
      int p = atomicAdd(&g_cur[d], 1);
      g_csrc[p] = src[i];
    }
  }
  for (int i = cb * 256 + threadIdx.x; i < N_NODES; i += stride) {
    int sp = c2s[i];
    if (sp >= slo && sp < shi) {
      int p = atomicAdd(&g_curs[sp], 1);
      g_cnode[p] = i;
    }
  }
}

// ---------------- MFMA bf16x3 GEMM: out[nrows x 96] (R10-proven) -----------
// fp32 operands split a = ah + al (bf16 RTN); D = al*bh + ah*bl + ah*bh.
// W staged+split in LDS. STATS: per-block column partials.
// A: row=l&15, k=(l>>4)*8+j; B: col=l&15; C/D: col=l&15, row=(l>>4)*4+j [m89].
template <int K, bool AFF, bool SCALE, bool STATS>
__global__ __launch_bounds__(256) void k_mfma(const float* __restrict__ Aext,
                                              int a_id, int out_id,
                                              const float* __restrict__ W,
                                              const float* __restrict__ bias,
                                              int stage, int nrows) {
  constexpr int CH = K / 32;
  __shared__ unsigned short WF[CH][6][64][8];   // hi fragments
  __shared__ unsigned short WL[CH][6][64][8];   // lo fragments
  __shared__ float abs_[2 * HID];
  __shared__ float bs[HID];
  const float* A = Aext ? Aext : pick(a_id);
  float* out = pick(out_id);
  int tid = threadIdx.x;
  if (AFF && tid < 2 * HID) abs_[tid] = g_ab[stage * 2 * HID + tid];
  if (tid < HID) bs[tid] = bias ? bias[tid] : 0.f;
  for (int idx = tid; idx < CH * 6 * 64; idx += 256) {
    int lane = idx & 63;
    int ct = (idx >> 6) % 6;
    int ch = idx / (6 * 64);
    int kbase = ch * 32 + (lane >> 4) * 8;
    int c = ct * 16 + (lane & 15);
#pragma unroll
    for (int j = 0; j < 8; ++j) {
      float w = W[(size_t)(kbase + j) * HID + c];
      unsigned short h = bf16_rn(w);
      WF[ch][ct][lane][j] = h;
      WL[ch][ct][lane][j] = bf16_rn(w - __uint_as_float((unsigned)h << 16));
    }
  }
  __syncthreads();

  int wv = tid >> 6, lane = tid & 63;
  int r0 = blockIdx.x * 64 + wv * 16;
  int arow = r0 + (lane & 15);
  f32x4 acc[6];
#pragma unroll
  for (int t = 0; t < 6; ++t) acc[t] = (f32x4){0.f, 0.f, 0.f, 0.f};

  for (int ch = 0; ch < CH; ++ch) {
    int ks = ch * 32 + (lane >> 4) * 8;
    float av[8];
    if (arow < nrows) {
      const float4* ap = reinterpret_cast<const float4*>(A + (size_t)arow * K + ks);
      float4 v0 = ap[0], v1 = ap[1];
      av[0] = v0.x; av[1] = v0.y; av[2] = v0.z; av[3] = v0.w;
      av[4] = v1.x; av[5] = v1.y; av[6] = v1.z; av[7] = v1.w;
    } else {
#pragma unroll
      for (int j = 0; j < 8; ++j) av[j] = 0.f;
    }
    if (AFF) {
#pragma unroll
      for (int j = 0; j < 8; ++j)
        av[j] = fmaxf(av[j] * abs_[ks + j] + abs_[HID + ks + j], 0.f);
    }
    bf16x8 ah, al;
#pragma unroll
    for (int j = 0; j < 8; ++j) {
      unsigned short h = bf16_rn(av[j]);
      ah[j] = (short)h;
      al[j] = (short)bf16_rn(av[j] - __uint_as_float((unsigned)h << 16));
    }
#pragma unroll
    for (int ct = 0; ct < 6; ++ct) {
      bf16x8 bh = *reinterpret_cast<const bf16x8*>(&WF[ch][ct][lane][0]);
      bf16x8 bl = *reinterpret_cast<const bf16x8*>(&WL[ch][ct][lane][0]);
      acc[ct] = __builtin_amdgcn_mfma_f32_16x16x32_bf16(al, bh, acc[ct], 0, 0, 0);
      acc[ct] = __builtin_amdgcn_mfma_f32_16x16x32_bf16(ah, bl, acc[ct], 0, 0, 0);
      acc[ct] = __builtin_amdgcn_mfma_f32_16x16x32_bf16(ah, bh, acc[ct], 0, 0, 0);
    }
  }
  int rbase = r0 + (lane >> 4) * 4;
  float dv[4];
#pragma unroll
  for (int j = 0; j < 4; ++j) {
    int r = rbase + j;
    dv[j] = SCALE ? ((r < nrows) ? g_dinv[r] : 0.f) : 1.f;
  }
  float s1[6], s2[6];
#pragma unroll
  for (int ct = 0; ct < 6; ++ct) { s1[ct] = 0.f; s2[ct] = 0.f; }
#pragma unroll
  for (int ct = 0; ct < 6; ++ct) {
    int col = ct * 16 + (lane & 15);
    float bb = bs[col];
#pragma unroll
    for (int j = 0; j < 4; ++j) {
      int r = rbase + j;
      if (r < nrows) {
        float v = acc[ct][j] * dv[j] + bb;
        out[(size_t)r * HID + col] = v;
        if (STATS) { s1[ct] += v; s2[ct] += v * v; }
      }
    }
  }
  if constexpr (STATS) {
#pragma unroll
    for (int o = 16; o <= 32; o <<= 1) {
#pragma unroll
      for (int ct = 0; ct < 6; ++ct) {
        s1[ct] += __shfl_xor(s1[ct], o);
        s2[ct] += __shfl_xor(s2[ct], o);
      }
    }
    __shared__ float sr1[4][6][16], sr2[4][6][16];
    if (lane < 16) {
#pragma unroll
      for (int ct = 0; ct < 6; ++ct) {
        sr1[wv][ct][lane] = s1[ct];
        sr2[wv][ct][lane] = s2[ct];
      }
    }
    __syncthreads();
    if (tid < 2 * HID) {
      int c = (tid < HID) ? tid : tid - HID;
      int ct = c >> 4, l = c & 15;
      float s = 0.f;
#pragma unroll
      for (int w = 0; w < 4; ++w)
        s += (tid < HID) ? sr1[w][ct][l] : sr2[w][ct][l];
      g_gpart[blockIdx.x][tid] = s;
    }
  }
}

// ---------------- vector GEMM (MLP head) + stats partials ------------------
template <int K, bool AFF, bool SCALE, bool STATS>
__global__ __launch_bounds__(256) void k_gemm96(const float* __restrict__ Aext,
                                                int a_id, int out_id,
                                                const float* __restrict__ W,
                                                const float* __restrict__ bias,
                                                int stage, int nrows) {
  constexpr int KC = 32;
  constexpr int ROWS = 64;
  __shared__ __align__(16) float Ws[KC][HID];
  __shared__ float xs[ROWS][KC + 1];
  __shared__ float abs_[2 * HID];
  const float* A = Aext ? Aext : pick(a_id);
  float* out = pick(out_id);
  int tid = threadIdx.x;
  if (AFF && tid < 2 * HID) abs_[tid] = g_ab[stage * 2 * HID + tid];
  int r0 = blockIdx.x * ROWS;
  int rg = tid >> 3;
  int cg = (tid & 7) * 12;
  float acc[2][12];
#pragma unroll
  for (int i = 0; i < 2; ++i)
#pragma unroll
    for (int c = 0; c < 12; ++c) acc[i][c] = 0.f;

  for (int k0 = 0; k0 < K; k0 += KC) {
    __syncthreads();
    for (int f = tid; f < KC * HID / 4; f += 256) {
      reinterpret_cast<float4*>(&Ws[0][0])[f] =
          reinterpret_cast<const float4*>(W + (size_t)k0 * HID)[f];
    }
    for (int f = tid; f < ROWS * KC / 4; f += 256) {
      int r = f >> 3;
      int kk = (f & 7) << 2;
      int row = r0 + r;
      float4 v = make_float4(0.f, 0.f, 0.f, 0.f);
      if (row < nrows)
        v = *reinterpret_cast<const float4*>(A + (size_t)row * K + k0 + kk);
      if (AFF) {
        int c = k0 + kk;
        v.x = fmaxf(v.x * abs_[c]     + abs_[HID + c],     0.f);
        v.y = fmaxf(v.y * abs_[c + 1] + abs_[HID + c + 1], 0.f);
        v.z = fmaxf(v.z * abs_[c + 2] + abs_[HID + c + 2], 0.f);
        v.w = fmaxf(v.w * abs_[c + 3] + abs_[HID + c + 3], 0.f);
      }
      xs[r][kk] = v.x; xs[r][kk + 1] = v.y; xs[r][kk + 2] = v.z; xs[r][kk + 3] = v.w;
    }
    __syncthreads();
#pragma unroll
    for (int k = 0; k < KC; ++k) {
      float x0 = xs[rg][k];
      float x1 = xs[rg + 32][k];
#pragma unroll
      for (int c = 0; c < 12; ++c) {
        float wv = Ws[k][cg + c];
        acc[0][c] += x0 * wv;
        acc[1][c] += x1 * wv;
      }
    }
  }
  float s1[12], s2[12];
#pragma unroll
  for (int c = 0; c < 12; ++c) { s1[c] = 0.f; s2[c] = 0.f; }
#pragma unroll
  for (int i = 0; i < 2; ++i) {
    int row = r0 + rg + 32 * i;
    if (row < nrows) {
      float sc = SCALE ? g_dinv[row] : 1.f;
#pragma unroll
      for (int c = 0; c < 12; ++c) {
        float v = acc[i][c] * sc;
        if (bias) v += bias[cg + c];
        out[(size_t)row * HID + cg + c] = v;
        if (STATS) { s1[c] += v; s2[c] += v * v; }
      }
    }
  }
  if constexpr (STATS) {
#pragma unroll
    for (int off = 8; off <= 32; off <<= 1) {
#pragma unroll
      for (int c = 0; c < 12; ++c) {
        s1[c] += __shfl_xor(s1[c], off);
        s2[c] += __shfl_xor(s2[c], off);
      }
    }
    __shared__ float sred[4][8][24];
    int wv = tid >> 6, ln = tid & 63;
    if (ln < 8) {
#pragma unroll
      for (int c = 0; c < 12; ++c) {
        sred[wv][ln][2 * c] = s1[c];
        sred[wv][ln][2 * c + 1] = s2[c];
      }
    }
    __syncthreads();
    if (tid < 192) {
      int cg2 = tid / 24, j = tid % 24;
      float s = sred[0][cg2][j] + sred[1][cg2][j] + sred[2][cg2][j] + sred[3][cg2][j];
      int col = cg2 * 12 + (j >> 1);
      g_gpart[blockIdx.x][(j & 1) ? HID + col : col] = s;
    }
  }
}

// ---------------- GCN aggregation via CSR gather (+ block stat partials) ----
__global__ __launch_bounds__(256) void k_gather(int t_id, const float* __restrict__ b,
                                                int agg_id) {
  const float* __restrict__ t = pick(t_id);
  float* __restrict__ agg = pick(agg_id);
  int g = (blockIdx.x * 256 + threadIdx.x) >> 5;
  int lane = threadIdx.x & 31;
  int beg = g_rp[g], end = g_rp[g + 1];
  const float* __restrict__ tg = t + (size_t)g * HID;
  float a0 = tg[lane], a1 = tg[32 + lane], a2 = tg[64 + lane];
  int e = beg;
  for (; e + 8 <= end; e += 8) {
    const float* p0 = t + (size_t)g_csrc[e]     * HID;
    const float* p1 = t + (size_t)g_csrc[e + 1] * HID;
    const float* p2 = t + (size_t)g_csrc[e + 2] * HID;
    const float* p3 = t + (size_t)g_csrc[e + 3] * HID;
    const float* p4 = t + (size_t)g_csrc[e + 4] * HID;
    const float* p5 = t + (size_t)g_csrc[e + 5] * HID;
    const float* p6 = t + (size_t)g_csrc[e + 6] * HID;
    const float* p7 = t + (size_t)g_csrc[e + 7] * HID;
    a0 += p0[lane]; a1 += p0[32 + lane]; a2 += p0[64 + lane];
    a0 += p1[lane]; a1 += p1[32 + lane]; a2 += p1[64 + lane];
    a0 += p2[lane]; a1 += p2[32 + lane]; a2 += p2[64 + lane];
    a0 += p3[lane]; a1 += p3[32 + lane]; a2 += p3[64 + lane];
    a0 += p4[lane]; a1 += p4[32 + lane]; a2 += p4[64 + lane];
    a0 += p5[lane]; a1 += p5[32 + lane]; a2 += p5[64 + lane];
    a0 += p6[lane]; a1 += p6[32 + lane]; a2 += p6[64 + lane];
    a0 += p7[lane]; a1 += p7[32 + lane]; a2 += p7[64 + lane];
  }
  for (; e < end; ++e) {
    const float* __restrict__ ts = t + (size_t)g_csrc[e] * HID;
    a0 += ts[lane]; a1 += ts[32 + lane]; a2 += ts[64 + lane];
  }
  float di = g_dinv[g];
  float v0 = di * a0 + b[lane];
  float v1 = di * a1 + b[32 + lane];
  float v2 = di * a2 + b[64 + lane];
  size_t o = (size_t)g * HID;
  agg[o + lane]      = v0;
  agg[o + 32 + lane] = v1;
  agg[o + 64 + lane] = v2;
  float q0 = v0, q1 = v1, q2 = v2;
  float r0s = v0 * v0, r1s = v1 * v1, r2s = v2 * v2;
  q0 += __shfl_xor(q0, 32); r0s += __shfl_xor(r0s, 32);
  q1 += __shfl_xor(q1, 32); r1s += __shfl_xor(r1s, 32);
  q2 += __shfl_xor(q2, 32); r2s += __shfl_xor(r2s, 32);
  __shared__ float sred[4][32][6];
  int wv = threadIdx.x >> 6, ln = threadIdx.x & 63;
  if (ln < 32) {
    sred[wv][ln][0] = q0;  sred[wv][ln][1] = r0s;
    sred[wv][ln][2] = q1;  sred[wv][ln][3] = r1s;
    sred[wv][ln][4] = q2;  sred[wv][ln][5] = r2s;
  }
  __syncthreads();
  if (threadIdx.x < 192) {
    int l2 = threadIdx.x / 6, j = threadIdx.x % 6;
    float s = sred[0][l2][j] + sred[1][l2][j] + sred[2][l2][j] + sred[3][l2][j];
    int dim = l2 + (j >> 1) * 32;
    g_gpart[blockIdx.x][(j & 1) ? HID + dim : dim] = s;
  }
}

// ---------------- colred: reduce g_gpart[count] -> g_Spart[CSB] ------------
// 4 independent accumulator chains (latency-bound: keep loads in flight).
__global__ __launch_bounds__(256) void k_colred(int count) {
  int tid = threadIdx.x;
  if (tid >= 2 * HID) return;
  float a0 = 0.f, a1 = 0.f, a2 = 0.f, a3 = 0.f;
  int k = blockIdx.x;
  int step = gridDim.x;
  for (; k + 3 * step < count; k += 4 * step) {
    a0 += g_gpart[k][tid];
    a1 += g_gpart[k + step][tid];
    a2 += g_gpart[k + 2 * step][tid];
    a3 += g_gpart[k + 3 * step][tid];
  }
  for (; k < count; k += step) a0 += g_gpart[k][tid];
  g_Spart[blockIdx.x][tid] = (a0 + a1) + (a2 + a3);
}

// ---------------- gnreduce: sum partial rows + compute alpha/beta ----------
// 16 independent accumulator chains (single block; ILP is the only latency hiding).
__global__ __launch_bounds__(256) void k_gnreduce(int stage, const float* __restrict__ w,
                                                  const float* __restrict__ b,
                                                  const float* __restrict__ a,
                                                  float invn, int fromGpart, int count) {
  const float (*__restrict__ arr)[2 * HID] = fromGpart ? g_gpart : g_Spart;
  __shared__ float S[2 * HID];
  int tid = threadIdx.x;
  if (tid < 2 * HID) {
    float ac[16];
#pragma unroll
    for (int j = 0; j < 16; ++j) ac[j] = 0.f;
    int k = 0;
    for (; k + 16 <= count; k += 16) {
#pragma unroll
      for (int j = 0; j < 16; ++j) ac[j] += arr[k + j][tid];
    }
    for (; k < count; ++k) ac[0] += arr[k][tid];
    float s = (((ac[0] + ac[1]) + (ac[2] + ac[3])) + ((ac[4] + ac[5]) + (ac[6] + ac[7]))) +
              (((ac[8] + ac[9]) + (ac[10] + ac[11])) + ((ac[12] + ac[13]) + (ac[14] + ac[15])));
    S[tid] = s;
  }
  __syncthreads();
  if (tid < HID) {
    float mean = S[tid] * invn;
    float var = S[HID + tid] * invn + mean * mean * (a[tid] * a[tid] - 2.f * a[tid]);
    float r = rsqrtf(var + GN_EPS);
    float alpha = w[tid] * r;
    g_ab[stage * 2 * HID + tid] = alpha;
    g_ab[stage * 2 * HID + HID + tid] = b[tid] - alpha * a[tid] * mean;
  }
}

// ---------------- attention scores (fused GN affine on input) --------------
__global__ __launch_bounds__(256) void k_scores(int h_id, int stage,
                                                const float* __restrict__ W1,
                                                const float* __restrict__ b1,
                                                const float* __restrict__ W2,
                                                const float* __restrict__ b2) {
  __shared__ float W1s[HID * ATTN_HID];
  __shared__ float b1s[ATTN_HID], W2s[ATTN_HID];
  __shared__ float abs_[2 * HID];
  const float* h = pick(h_id);
  const float* ab = g_ab + stage * 2 * HID;
  int tid = threadIdx.x;
  for (int f = tid; f < HID * ATTN_HID; f += 256) W1s[f] = W1[f];
  if (tid < ATTN_HID) { b1s[tid] = b1[tid]; W2s[tid] = W2[tid]; }
  if (tid < 2 * HID) abs_[tid] = ab[tid];
  __syncthreads();
  int i = blockIdx.x * 256 + tid;
  if (i >= N_NODES) return;
  float acc[ATTN_HID];
#pragma unroll
  for (int k = 0; k < ATTN_HID; ++k) acc[k] = 0.f;
  const float4* h4 = reinterpret_cast<const float4*>(h + (size_t)i * HID);
  for (int j4 = 0; j4 < HID / 4; ++j4) {
    float4 hv4 = h4[j4];
    int j = j4 * 4;
    float h0 = fmaxf(hv4.x * abs_[j]     + abs_[HID + j],     0.f);
    float h1 = fmaxf(hv4.y * abs_[j + 1] + abs_[HID + j + 1], 0.f);
    float h2 = fmaxf(hv4.z * abs_[j + 2] + abs_[HID + j + 2], 0.f);
    float h3 = fmaxf(hv4.w * abs_[j + 3] + abs_[HID + j + 3], 0.f);
#pragma unroll
    for (int k = 0; k < ATTN_HID; ++k) {
      acc[k] += h0 * W1s[j * ATTN_HID + k] + h1 * W1s[(j + 1) * ATTN_HID + k] +
                h2 * W1s[(j + 2) * ATTN_HID + k] + h3 * W1s[(j + 3) * ATTN_HID + k];
    }
  }
  float s = b2[0];
#pragma unroll
  for (int k = 0; k < ATTN_HID; ++k) s += fmaxf(acc[k] + b1s[k], 0.f) * W2s[k];
  g_scores[i] = s;
}

// ---------------- segment softmax + weighted aggregation (CSR, no atomics) -
__global__ __launch_bounds__(256) void k_spotagg(int h_id, int stage) {
  const float* __restrict__ h = pick(h_id);
  const float* ab = g_ab + stage * 2 * HID;
  int g = (blockIdx.x * 256 + threadIdx.x) >> 5;
  int lane = threadIdx.x & 31;
  if (g >= N_SPOTS) return;
  int beg = g_rps[g], end = g_rps[g + 1];
  float m = -1e30f;
  for (int i = beg + lane; i < end; i += 32) m = fmaxf(m, g_scores[g_cnode[i]]);
#pragma unroll
  for (int o = 16; o >= 1; o >>= 1) m = fmaxf(m, __shfl_xor(m, o, 32));
  float al0 = ab[lane],      be0 = ab[HID + lane];
  float al1 = ab[32 + lane], be1 = ab[HID + 32 + lane];
  float al2 = ab[64 + lane], be2 = ab[HID + 64 + lane];
  float a0 = 0.f, a1 = 0.f, a2 = 0.f, denom = 0.f;
  for (int i = beg; i < end; ++i) {
    int nd = g_cnode[i];
    float e = __expf(g_scores[nd] - m);
    denom += e;
    const float* __restrict__ hr = h + (size_t)nd * HID;
    a0 += e * fmaxf(hr[lane] * al0 + be0, 0.f);
    a1 += e * fmaxf(hr[32 + lane] * al1 + be1, 0.f);
    a2 += e * fmaxf(hr[64 + lane] * al2 + be2, 0.f);
  }
  float inv = (denom > 0.f) ? 1.f / denom : 0.f;
  g_spot[g * HID + lane]      = a0 * inv;
  g_spot[g * HID + 32 + lane] = a1 * inv;
  g_spot[g * HID + 64 + lane] = a2 * inv;
}

// ---------------- final: out = relu(gn(t3)) @ mlp_W2 + b2 ------------------
__global__ __launch_bounds__(256) void k_final(int t3_id, int stage,
                                               const float* __restrict__ W2,
                                               const float* __restrict__ b2,
                                               float* __restrict__ out) {
  __shared__ float W2s[HID * OUT_DIM];
  const float* t3 = pick(t3_id);
  const float* ab = g_ab + stage * 2 * HID;
  int tid = threadIdx.x;
  for (int f = tid; f < HID * OUT_DIM; f += 256) W2s[f] = W2[f];
  __syncthreads();
  int r = blockIdx.x * 16 + (tid >> 4);
  int c = tid & 15;
  if (r >= N_SPOTS) return;
  float acc = b2[c];
  for (int j = 0; j < HID; ++j) {
    float z = fmaxf(t3[(size_t)r * HID + j] * ab[j] + ab[HID + j], 0.f);
    acc += z * W2s[j * OUT_DIM + c];
  }
  out[r * OUT_DIM + c] = acc;
}

// ---------------------------------------------------------------------------
extern "C" void kernel_launch(void* const* d_in, const int* in_sizes, int n_in,
                              void* d_out, int out_size, void* d_ws, size_t ws_size,
                              hipStream_t stream) {
  const float* x       = (const float*)d_in[0];
  const int*   ei      = (const int*)d_in[1];
  const int*   src     = ei;
  const int*   dst     = ei + N_EDGES;
  const int*   c2s     = (const int*)d_in[2];
  const float* proj_W  = (const float*)d_in[4];
  const float* proj_b  = (const float*)d_in[5];
  const float* gn0_w   = (const float*)d_in[6];
  const float* gn0_b   = (const float*)d_in[7];
  const float* gn0_a   = (const float*)d_in[8];
  const float* gcn1_W  = (const float*)d_in[9];
  const float* gcn1_b  = (const float*)d_in[10];
  const float* gn1_w   = (const float*)d_in[11];
  const float* gn1_b   = (const float*)d_in[12];
  const float* gn1_a   = (const float*)d_in[13];
  const float* gcn2_W  = (const float*)d_in[14];
  const float* gcn2_b  = (const float*)d_in[15];
  const float* gn2_w   = (const float*)d_in[16];
  const float* gn2_b   = (const float*)d_in[17];
  const float* gn2_a   = (const float*)d_in[18];
  const float* attn_W1 = (const float*)d_in[19];
  const float* attn_b1 = (const float*)d_in[20];
  const float* attn_W2 = (const float*)d_in[21];
  const float* attn_b2 = (const float*)d_in[22];
  const float* mlp_W1  = (const float*)d_in[23];
  const float* mlp_b1  = (const float*)d_in[24];
  const float* mlp_gn_w = (const float*)d_in[25];
  const float* mlp_gn_b = (const float*)d_in[26];
  const float* mlp_gn_a = (const float*)d_in[27];
  const float* mlp_W2  = (const float*)d_in[28];
  const float* mlp_b2  = (const float*)d_in[29];
  float* out = (float*)d_out;

  const float invN = 1.f / (float)N_NODES;
  const float invS = 1.f / (float)N_SPOTS;
  const int MFB  = (N_NODES + 63) / 64;     // 782
  const int GB_S = (N_SPOTS + 63) / 64;     // 79
  const int XB   = NXCD * 96;               // 768
  const int SPB  = (N_SPOTS * 32 + 255) / 256;

  // ---- CSR build ----
  k_init<<<(N_NODES + 255) / 256, 256, 0, stream>>>();
  k_hist<<<XB, 256, 0, stream>>>(dst, c2s);
  k_scan1<<<SCB, 256, 0, stream>>>();
  k_scan3<<<SCB, 256, 0, stream>>>();   // inline prefix replaces scan2
  k_fill<<<XB, 256, 0, stream>>>(src, dst, c2s);

  // ---- stage 0: proj (MFMA bf16x3, stats fused into epilogue) ----
  k_mfma<IN_DIM, false, false, true><<<MFB, 256, 0, stream>>>(x, -1, 0, proj_W, proj_b, 0, N_NODES);
  k_colred<<<CSB, 256, 0, stream>>>(MFB);
  k_gnreduce<<<1, 256, 0, stream>>>(0, gn0_w, gn0_b, gn0_a, invN, 0, CSB);

  // ---- GCN layer 1 ----
  k_mfma<HID, true, true, false><<<MFB, 256, 0, stream>>>(nullptr, 0, 1, gcn1_W, nullptr, 0, N_NODES);
  k_gather<<<GTHB, 256, 0, stream>>>(1, gcn1_b, 0);
  k_colred<<<CSB, 256, 0, stream>>>(GTHB);
  k_gnreduce<<<1, 256, 0, stream>>>(1, gn1_w, gn1_b, gn1_a, invN, 0, CSB);

  // ---- GCN layer 2 ----
  k_mfma<HID, true, true, false><<<MFB, 256, 0, stream>>>(nullptr, 0, 2, gcn2_W, nullptr, 1, N_NODES);
  k_gather<<<GTHB, 256, 0, stream>>>(2, gcn2_b, 1);
  k_colred<<<CSB, 256, 0, stream>>>(GTHB);
  k_gnreduce<<<1, 256, 0, stream>>>(2, gn2_w, gn2_b, gn2_a, invN, 0, CSB);

  // ---- attention + segment softmax + spot aggregation ----
  k_scores<<<(N_NODES + 255) / 256, 256, 0, stream>>>(1, 2, attn_W1, attn_b1, attn_W2, attn_b2);
  k_spotagg<<<SPB, 256, 0, stream>>>(1, 2);

  // ---- MLP head (stats fused; gnreduce reads g_gpart directly) ----
  k_gemm96<HID, false, false, true><<<GB_S, 256, 0, stream>>>(nullptr, 3, 2, mlp_W1, mlp_b1, 0, N_SPOTS);
  k_gnreduce<<<1, 256, 0, stream>>>(3, mlp_gn_w, mlp_gn_b, mlp_gn_a, invS, 1, GB_S);
  k_final<<<(N_SPOTS + 15) / 16, 256, 0, stream>>>(2, 3, mlp_W2, mlp_b2, out);
}

// Round 14
// 351.693 us; speedup vs baseline: 1.5377x; 1.0165x over previous
//
#include <hip/hip_runtime.h>

#define N_NODES 50000
#define N_EDGES 800000
#define IN_DIM 128
#define HID 96
#define ATTN_HID 32
#define OUT_DIM 16
#define N_SPOTS 5000
#define GN_EPS 1e-5f

#define SCAN_NB ((N_NODES + 255) / 256)   // 196
#define SCAN_SB ((N_SPOTS + 255) / 256)   // 20
#define SCB (SCAN_NB + SCAN_SB)           // 216
#define NXCD 8
#define NRANGE (N_NODES / NXCD)           // 6250
#define SRANGE (N_SPOTS / NXCD)           // 625
#define CSB 256                           // colred blocks
#define GTHB 6250                         // gather blocks

typedef short bf16x8 __attribute__((ext_vector_type(8)));
typedef float f32x4 __attribute__((ext_vector_type(4)));

// ---------------- persistent device scratch (re-initialized every call) ----
__device__ __align__(16) float g_bufA[N_NODES * HID];
__device__ __align__(16) float g_bufB[N_NODES * HID];
__device__ __align__(16) float g_bufC[N_NODES * HID];
__device__ __align__(16) float g_spot[N_SPOTS * HID];
__device__ float    g_dinv[N_NODES];      // rsqrt(deg+1)
__device__ float    g_scores[N_NODES];
__device__ int      g_deg[N_NODES];       // in-degree histogram (edges)
__device__ int      g_degs[N_SPOTS];      // spot histogram (nodes)
__device__ int      g_rp[N_NODES + 1];    // CSR row ptr (by dst)
__device__ int      g_cur[N_NODES];       // fill cursors
__device__ int      g_rps[N_SPOTS + 1];   // spot CSR row ptr
__device__ int      g_curs[N_SPOTS];
__device__ int      g_csrc[N_EDGES];      // CSR src indices
__device__ int      g_cnode[N_NODES];     // spot CSR node indices
__device__ int      g_partN[SCAN_NB];     // scan partials (RAW block totals)
__device__ int      g_partS[SCAN_SB];
__device__ float    g_gpart[GTHB][2 * HID]; // per-block stat partials (no atomics)
__device__ float    g_Spart[CSB][2 * HID];  // 2nd-level stat partials
__device__ float    g_ab[4 * 2 * HID];    // 4 GN stages x (alpha, beta)
// pre-split W fragments (hi/lo), frag-ordered: off = ((ch*6+ct)<<9)+(lane<<3)+j
__device__ __align__(16) unsigned short g_wf[3][4 * 6 * 64 * 8];
__device__ __align__(16) unsigned short g_wl[3][4 * 6 * 64 * 8];

__device__ __forceinline__ float* pick(int id) {
  switch (id) {
    case 0:  return g_bufA;
    case 1:  return g_bufB;
    case 2:  return g_bufC;
    default: return g_spot;
  }
}

__device__ __forceinline__ unsigned short bf16_rn(float f) {
  unsigned u = __float_as_uint(f);
  unsigned r = u + 0x7FFFu + ((u >> 16) & 1u);
  return (unsigned short)(r >> 16);
}

// ---------------- init: zero histograms + split W to frag order ------------
// W tiles: proj 4ch x 6ct = 24, gcn1 18, gcn2 18 -> 60 tiles, one per block.
// (R8-verified split code; resource-light pack with the zeroing — no LDS.)
__global__ __launch_bounds__(256) void k_init(const float* __restrict__ pW,
                                              const float* __restrict__ w1,
                                              const float* __restrict__ w2) {
  int i = blockIdx.x * 256 + threadIdx.x;
  if (i < N_NODES) g_deg[i] = 0;
  if (i < N_SPOTS) g_degs[i] = 0;
  int b = blockIdx.x;
  if (b < 60 && threadIdx.x < 64) {
    int lane = threadIdx.x;
    int m, lb;
    const float* W;
    if (b < 24)      { m = 0; lb = b;      W = pW; }
    else if (b < 42) { m = 1; lb = b - 24; W = w1; }
    else             { m = 2; lb = b - 42; W = w2; }
    int ch = lb / 6, ct = lb % 6;
    int kbase = ch * 32 + (lane >> 4) * 8;
    int c = ct * 16 + (lane & 15);
    int off = ((ch * 6 + ct) << 9) + (lane << 3);
#pragma unroll
    for (int j = 0; j < 8; ++j) {
      float w = W[(size_t)(kbase + j) * HID + c];
      unsigned short h = bf16_rn(w);
      g_wf[m][off + j] = h;
      g_wl[m][off + j] = bf16_rn(w - __uint_as_float((unsigned)h << 16));
    }
  }
}

// ---------------- XCD-local histograms ------------------------------------
__global__ __launch_bounds__(256) void k_hist(const int* __restrict__ dst,
                                              const int* __restrict__ c2s) {
  int r = blockIdx.x & 7;
  int cb = blockIdx.x >> 3;
  int stride = (gridDim.x >> 3) * 256;
  int nlo = r * NRANGE, nhi = nlo + NRANGE;
  int slo = r * SRANGE, shi = slo + SRANGE;
  for (int i = cb * 256 + threadIdx.x; i < N_EDGES; i += stride) {
    int d = dst[i];
    if (d >= nlo && d < nhi) atomicAdd(&g_deg[d], 1);
  }
  for (int i = cb * 256 + threadIdx.x; i < N_NODES; i += stride) {
    int sp = c2s[i];
    if (sp >= slo && sp < shi) atomicAdd(&g_degs[sp], 1);
  }
}

// ---------------- scan phase 1: raw per-block totals -----------------------
__global__ __launch_bounds__(256) void k_scan1() {
  bool isS = blockIdx.x >= SCAN_NB;
  int b = isS ? blockIdx.x - SCAN_NB : blockIdx.x;
  const int n = isS ? N_SPOTS : N_NODES;
  const int* deg = isS ? g_degs : g_deg;
  int i = b * 256 + threadIdx.x;
  int v = (i < n) ? deg[i] : 0;
#pragma unroll
  for (int o = 32; o >= 1; o >>= 1) v += __shfl_xor(v, o);
  __shared__ int red[4];
  if ((threadIdx.x & 63) == 0) red[threadIdx.x >> 6] = v;
  __syncthreads();
  if (threadIdx.x == 0)
    (isS ? g_partS : g_partN)[b] = red[0] + red[1] + red[2] + red[3];
}

// ---------------- scan phase 3 with inline prefix (replaces scan2) ---------
__global__ __launch_bounds__(256) void k_scan3() {
  bool isS = blockIdx.x >= SCAN_NB;
  int b = isS ? blockIdx.x - SCAN_NB : blockIdx.x;
  const int n = isS ? N_SPOTS : N_NODES;
  const int* deg = isS ? g_degs : g_deg;
  int* rp  = isS ? g_rps  : g_rp;
  int* cur = isS ? g_curs : g_cur;
  const int* part = isS ? g_partS : g_partN;  // RAW totals
  int t = threadIdx.x;
  int pv = (t < b) ? part[t] : 0;
#pragma unroll
  for (int o = 32; o >= 1; o >>= 1) pv += __shfl_xor(pv, o);
  __shared__ int red3[4];
  if ((t & 63) == 0) red3[t >> 6] = pv;
  __syncthreads();
  int base = red3[0] + red3[1] + red3[2] + red3[3];
  __shared__ int tmp[256];
  int i = b * 256 + t;
  int v = (i < n) ? deg[i] : 0;
  tmp[t] = v;
  __syncthreads();
  for (int o = 1; o < 256; o <<= 1) {
    int u = (t >= o) ? tmp[t - o] : 0;
    __syncthreads();
    tmp[t] += u;
    __syncthreads();
  }
  if (i < n) {
    int off = base + tmp[t] - v;
    rp[i] = off;
    cur[i] = off;
    if (i == n - 1) rp[n] = off + v;
    if (!isS) g_dinv[i] = rsqrtf((float)(v + 1));
  }
}

// ---------------- XCD-local CSR fill ---------------------------------------
__global__ __launch_bounds__(256) void k_fill(const int* __restrict__ src,
                                              const int* __restrict__ dst,
                                              const int* __restrict__ c2s) {
  int r = blockIdx.x & 7;
  int cb = blockIdx.x >> 3;
  int stride = (gridDim.x >> 3) * 256;
  int nlo = r * NRANGE, nhi = nlo + NRANGE;
  int slo = r * SRANGE, shi = slo + SRANGE;
  for (int i = cb * 256 + threadIdx.x; i < N_EDGES; i += stride) {
    int d = dst[i];
    if (d >= nlo && d < nhi) {
      int p = atomicAdd(&g_cur[d], 1);
      g_csrc[p] = src[i];
    }
  }
  for (int i = cb * 256 + threadIdx.x; i < N_NODES; i += stride) {
    int sp = c2s[i];
    if (sp >= slo && sp < shi) {
      int p = atomicAdd(&g_curs[sp], 1);
      g_cnode[p] = i;
    }
  }
}

// ---------------- MFMA bf16x3 GEMM: out[nrows x 96] ------------------------
// W fragments pre-split in g_wf/g_wl (k_init); staged to LDS via linear
// uint4 copy (global frag layout == LDS frag layout). Inner loop = R10.
// A: row=l&15, k=(l>>4)*8+j; B: col=l&15; C/D: col=l&15, row=(l>>4)*4+j [m89].
template <int K, bool AFF, bool SCALE, bool STATS>
__global__ __launch_bounds__(256) void k_mfma(const float* __restrict__ Aext,
                                              int a_id, int out_id, int m,
                                              const float* __restrict__ bias,
                                              int stage, int nrows) {
  constexpr int CH = K / 32;
  __shared__ __align__(16) unsigned short WF[CH][6][64][8];   // hi fragments
  __shared__ __align__(16) unsigned short WL[CH][6][64][8];   // lo fragments
  __shared__ float abs_[2 * HID];
  __shared__ float bs[HID];
  const float* A = Aext ? Aext : pick(a_id);
  float* out = pick(out_id);
  int tid = threadIdx.x;
  if (AFF && tid < 2 * HID) abs_[tid] = g_ab[stage * 2 * HID + tid];
  if (tid < HID) bs[tid] = bias ? bias[tid] : 0.f;
  // stage pre-split fragments: straight vector copy (CH*384 uint4 per array)
  {
    const uint4* __restrict__ gf = reinterpret_cast<const uint4*>(g_wf[m]);
    const uint4* __restrict__ gl = reinterpret_cast<const uint4*>(g_wl[m]);
    uint4* lf = reinterpret_cast<uint4*>(&WF[0][0][0][0]);
    uint4* ll = reinterpret_cast<uint4*>(&WL[0][0][0][0]);
    constexpr int NV = CH * 6 * 64;  // uint4 count (8 ushorts each)
    for (int f = tid; f < NV; f += 256) {
      lf[f] = gf[f];
      ll[f] = gl[f];
    }
  }
  __syncthreads();

  int wv = tid >> 6, lane = tid & 63;
  int r0 = blockIdx.x * 64 + wv * 16;
  int arow = r0 + (lane & 15);
  f32x4 acc[6];
#pragma unroll
  for (int t = 0; t < 6; ++t) acc[t] = (f32x4){0.f, 0.f, 0.f, 0.f};

  for (int ch = 0; ch < CH; ++ch) {
    int ks = ch * 32 + (lane >> 4) * 8;
    float av[8];
    if (arow < nrows) {
      const float4* ap = reinterpret_cast<const float4*>(A + (size_t)arow * K + ks);
      float4 v0 = ap[0], v1 = ap[1];
      av[0] = v0.x; av[1] = v0.y; av[2] = v0.z; av[3] = v0.w;
      av[4] = v1.x; av[5] = v1.y; av[6] = v1.z; av[7] = v1.w;
    } else {
#pragma unroll
      for (int j = 0; j < 8; ++j) av[j] = 0.f;
    }
    if (AFF) {
#pragma unroll
      for (int j = 0; j < 8; ++j)
        av[j] = fmaxf(av[j] * abs_[ks + j] + abs_[HID + ks + j], 0.f);
    }
    bf16x8 ah, al;
#pragma unroll
    for (int j = 0; j < 8; ++j) {
      unsigned short h = bf16_rn(av[j]);
      ah[j] = (short)h;
      al[j] = (short)bf16_rn(av[j] - __uint_as_float((unsigned)h << 16));
    }
#pragma unroll
    for (int ct = 0; ct < 6; ++ct) {
      bf16x8 bh = *reinterpret_cast<const bf16x8*>(&WF[ch][ct][lane][0]);
      bf16x8 bl = *reinterpret_cast<const bf16x8*>(&WL[ch][ct][lane][0]);
      acc[ct] = __builtin_amdgcn_mfma_f32_16x16x32_bf16(al, bh, acc[ct], 0, 0, 0);
      acc[ct] = __builtin_amdgcn_mfma_f32_16x16x32_bf16(ah, bl, acc[ct], 0, 0, 0);
      acc[ct] = __builtin_amdgcn_mfma_f32_16x16x32_bf16(ah, bh, acc[ct], 0, 0, 0);
    }
  }
  int rbase = r0 + (lane >> 4) * 4;
  float dv[4];
#pragma unroll
  for (int j = 0; j < 4; ++j) {
    int r = rbase + j;
    dv[j] = SCALE ? ((r < nrows) ? g_dinv[r] : 0.f) : 1.f;
  }
  float s1[6], s2[6];
#pragma unroll
  for (int ct = 0; ct < 6; ++ct) { s1[ct] = 0.f; s2[ct] = 0.f; }
#pragma unroll
  for (int ct = 0; ct < 6; ++ct) {
    int col = ct * 16 + (lane & 15);
    float bb = bs[col];
#pragma unroll
    for (int j = 0; j < 4; ++j) {
      int r = rbase + j;
      if (r < nrows) {
        float v = acc[ct][j] * dv[j] + bb;
        out[(size_t)r * HID + col] = v;
        if (STATS) { s1[ct] += v; s2[ct] += v * v; }
      }
    }
  }
  if constexpr (STATS) {
#pragma unroll
    for (int o = 16; o <= 32; o <<= 1) {
#pragma unroll
      for (int ct = 0; ct < 6; ++ct) {
        s1[ct] += __shfl_xor(s1[ct], o);
        s2[ct] += __shfl_xor(s2[ct], o);
      }
    }
    __shared__ float sr1[4][6][16], sr2[4][6][16];
    if (lane < 16) {
#pragma unroll
      for (int ct = 0; ct < 6; ++ct) {
        sr1[wv][ct][lane] = s1[ct];
        sr2[wv][ct][lane] = s2[ct];
      }
    }
    __syncthreads();
    if (tid < 2 * HID) {
      int c = (tid < HID) ? tid : tid - HID;
      int ct = c >> 4, l = c & 15;
      float s = 0.f;
#pragma unroll
      for (int w = 0; w < 4; ++w)
        s += (tid < HID) ? sr1[w][ct][l] : sr2[w][ct][l];
      g_gpart[blockIdx.x][tid] = s;
    }
  }
}

// ---------------- vector GEMM (MLP head) + stats partials ------------------
template <int K, bool AFF, bool SCALE, bool STATS>
__global__ __launch_bounds__(256) void k_gemm96(const float* __restrict__ Aext,
                                                int a_id, int out_id,
                                                const float* __restrict__ W,
                                                const float* __restrict__ bias,
                                                int stage, int nrows) {
  constexpr int KC = 32;
  constexpr int ROWS = 64;
  __shared__ __align__(16) float Ws[KC][HID];
  __shared__ float xs[ROWS][KC + 1];
  __shared__ float abs_[2 * HID];
  const float* A = Aext ? Aext : pick(a_id);
  float* out = pick(out_id);
  int tid = threadIdx.x;
  if (AFF && tid < 2 * HID) abs_[tid] = g_ab[stage * 2 * HID + tid];
  int r0 = blockIdx.x * ROWS;
  int rg = tid >> 3;
  int cg = (tid & 7) * 12;
  float acc[2][12];
#pragma unroll
  for (int i = 0; i < 2; ++i)
#pragma unroll
    for (int c = 0; c < 12; ++c) acc[i][c] = 0.f;

  for (int k0 = 0; k0 < K; k0 += KC) {
    __syncthreads();
    for (int f = tid; f < KC * HID / 4; f += 256) {
      reinterpret_cast<float4*>(&Ws[0][0])[f] =
          reinterpret_cast<const float4*>(W + (size_t)k0 * HID)[f];
    }
    for (int f = tid; f < ROWS * KC / 4; f += 256) {
      int r = f >> 3;
      int kk = (f & 7) << 2;
      int row = r0 + r;
      float4 v = make_float4(0.f, 0.f, 0.f, 0.f);
      if (row < nrows)
        v = *reinterpret_cast<const float4*>(A + (size_t)row * K + k0 + kk);
      if (AFF) {
        int c = k0 + kk;
        v.x = fmaxf(v.x * abs_[c]     + abs_[HID + c],     0.f);
        v.y = fmaxf(v.y * abs_[c + 1] + abs_[HID + c + 1], 0.f);
        v.z = fmaxf(v.z * abs_[c + 2] + abs_[HID + c + 2], 0.f);
        v.w = fmaxf(v.w * abs_[c + 3] + abs_[HID + c + 3], 0.f);
      }
      xs[r][kk] = v.x; xs[r][kk + 1] = v.y; xs[r][kk + 2] = v.z; xs[r][kk + 3] = v.w;
    }
    __syncthreads();
#pragma unroll
    for (int k = 0; k < KC; ++k) {
      float x0 = xs[rg][k];
      float x1 = xs[rg + 32][k];
#pragma unroll
      for (int c = 0; c < 12; ++c) {
        float wv = Ws[k][cg + c];
        acc[0][c] += x0 * wv;
        acc[1][c] += x1 * wv;
      }
    }
  }
  float s1[12], s2[12];
#pragma unroll
  for (int c = 0; c < 12; ++c) { s1[c] = 0.f; s2[c] = 0.f; }
#pragma unroll
  for (int i = 0; i < 2; ++i) {
    int row = r0 + rg + 32 * i;
    if (row < nrows) {
      float sc = SCALE ? g_dinv[row] : 1.f;
#pragma unroll
      for (int c = 0; c < 12; ++c) {
        float v = acc[i][c] * sc;
        if (bias) v += bias[cg + c];
        out[(size_t)row * HID + cg + c] = v;
        if (STATS) { s1[c] += v; s2[c] += v * v; }
      }
    }
  }
  if constexpr (STATS) {
#pragma unroll
    for (int off = 8; off <= 32; off <<= 1) {
#pragma unroll
      for (int c = 0; c < 12; ++c) {
        s1[c] += __shfl_xor(s1[c], off);
        s2[c] += __shfl_xor(s2[c], off);
      }
    }
    __shared__ float sred[4][8][24];
    int wv = tid >> 6, ln = tid & 63;
    if (ln < 8) {
#pragma unroll
      for (int c = 0; c < 12; ++c) {
        sred[wv][ln][2 * c] = s1[c];
        sred[wv][ln][2 * c + 1] = s2[c];
      }
    }
    __syncthreads();
    if (tid < 192) {
      int cg2 = tid / 24, j = tid % 24;
      float s = sred[0][cg2][j] + sred[1][cg2][j] + sred[2][cg2][j] + sred[3][cg2][j];
      int col = cg2 * 12 + (j >> 1);
      g_gpart[blockIdx.x][(j & 1) ? HID + col : col] = s;
    }
  }
}

// ---------------- GCN aggregation via CSR gather (+ block stat partials) ----
__global__ __launch_bounds__(256) void k_gather(int t_id, const float* __restrict__ b,
                                                int agg_id) {
  const float* __restrict__ t = pick(t_id);
  float* __restrict__ agg = pick(agg_id);
  int g = (blockIdx.x * 256 + threadIdx.x) >> 5;
  int lane = threadIdx.x & 31;
  int beg = g_rp[g], end = g_rp[g + 1];
  const float* __restrict__ tg = t + (size_t)g * HID;
  float a0 = tg[lane], a1 = tg[32 + lane], a2 = tg[64 + lane];
  int e = beg;
  for (; e + 8 <= end; e += 8) {
    const float* p0 = t + (size_t)g_csrc[e]     * HID;
    const float* p1 = t + (size_t)g_csrc[e + 1] * HID;
    const float* p2 = t + (size_t)g_csrc[e + 2] * HID;
    const float* p3 = t + (size_t)g_csrc[e + 3] * HID;
    const float* p4 = t + (size_t)g_csrc[e + 4] * HID;
    const float* p5 = t + (size_t)g_csrc[e + 5] * HID;
    const float* p6 = t + (size_t)g_csrc[e + 6] * HID;
    const float* p7 = t + (size_t)g_csrc[e + 7] * HID;
    a0 += p0[lane]; a1 += p0[32 + lane]; a2 += p0[64 + lane];
    a0 += p1[lane]; a1 += p1[32 + lane]; a2 += p1[64 + lane];
    a0 += p2[lane]; a1 += p2[32 + lane]; a2 += p2[64 + lane];
    a0 += p3[lane]; a1 += p3[32 + lane]; a2 += p3[64 + lane];
    a0 += p4[lane]; a1 += p4[32 + lane]; a2 += p4[64 + lane];
    a0 += p5[lane]; a1 += p5[32 + lane]; a2 += p5[64 + lane];
    a0 += p6[lane]; a1 += p6[32 + lane]; a2 += p6[64 + lane];
    a0 += p7[lane]; a1 += p7[32 + lane]; a2 += p7[64 + lane];
  }
  for (; e < end; ++e) {
    const float* __restrict__ ts = t + (size_t)g_csrc[e] * HID;
    a0 += ts[lane]; a1 += ts[32 + lane]; a2 += ts[64 + lane];
  }
  float di = g_dinv[g];
  float v0 = di * a0 + b[lane];
  float v1 = di * a1 + b[32 + lane];
  float v2 = di * a2 + b[64 + lane];
  size_t o = (size_t)g * HID;
  agg[o + lane]      = v0;
  agg[o + 32 + lane] = v1;
  agg[o + 64 + lane] = v2;
  float q0 = v0, q1 = v1, q2 = v2;
  float r0s = v0 * v0, r1s = v1 * v1, r2s = v2 * v2;
  q0 += __shfl_xor(q0, 32); r0s += __shfl_xor(r0s, 32);
  q1 += __shfl_xor(q1, 32); r1s += __shfl_xor(r1s, 32);
  q2 += __shfl_xor(q2, 32); r2s += __shfl_xor(r2s, 32);
  __shared__ float sred[4][32][6];
  int wv = threadIdx.x >> 6, ln = threadIdx.x & 63;
  if (ln < 32) {
    sred[wv][ln][0] = q0;  sred[wv][ln][1] = r0s;
    sred[wv][ln][2] = q1;  sred[wv][ln][3] = r1s;
    sred[wv][ln][4] = q2;  sred[wv][ln][5] = r2s;
  }
  __syncthreads();
  if (threadIdx.x < 192) {
    int l2 = threadIdx.x / 6, j = threadIdx.x % 6;
    float s = sred[0][l2][j] + sred[1][l2][j] + sred[2][l2][j] + sred[3][l2][j];
    int dim = l2 + (j >> 1) * 32;
    g_gpart[blockIdx.x][(j & 1) ? HID + dim : dim] = s;
  }
}

// ---------------- colred: reduce g_gpart[count] -> g_Spart[CSB] ------------
__global__ __launch_bounds__(256) void k_colred(int count) {
  int tid = threadIdx.x;
  if (tid >= 2 * HID) return;
  float a0 = 0.f, a1 = 0.f, a2 = 0.f, a3 = 0.f;
  int k = blockIdx.x;
  int step = gridDim.x;
  for (; k + 3 * step < count; k += 4 * step) {
    a0 += g_gpart[k][tid];
    a1 += g_gpart[k + step][tid];
    a2 += g_gpart[k + 2 * step][tid];
    a3 += g_gpart[k + 3 * step][tid];
  }
  for (; k < count; k += step) a0 += g_gpart[k][tid];
  g_Spart[blockIdx.x][tid] = (a0 + a1) + (a2 + a3);
}

// ---------------- gnreduce: 16-chain ILP reduce + compute alpha/beta -------
__global__ __launch_bounds__(256) void k_gnreduce(int stage, const float* __restrict__ w,
                                                  const float* __restrict__ b,
                                                  const float* __restrict__ a,
                                                  float invn, int fromGpart, int count) {
  const float (*__restrict__ arr)[2 * HID] = fromGpart ? g_gpart : g_Spart;
  __shared__ float S[2 * HID];
  int tid = threadIdx.x;
  if (tid < 2 * HID) {
    float ac[16];
#pragma unroll
    for (int j = 0; j < 16; ++j) ac[j] = 0.f;
    int k = 0;
    for (; k + 16 <= count; k += 16) {
#pragma unroll
      for (int j = 0; j < 16; ++j) ac[j] += arr[k + j][tid];
    }
    for (; k < count; ++k) ac[0] += arr[k][tid];
    float s = (((ac[0] + ac[1]) + (ac[2] + ac[3])) + ((ac[4] + ac[5]) + (ac[6] + ac[7]))) +
              (((ac[8] + ac[9]) + (ac[10] + ac[11])) + ((ac[12] + ac[13]) + (ac[14] + ac[15])));
    S[tid] = s;
  }
  __syncthreads();
  if (tid < HID) {
    float mean = S[tid] * invn;
    float var = S[HID + tid] * invn + mean * mean * (a[tid] * a[tid] - 2.f * a[tid]);
    float r = rsqrtf(var + GN_EPS);
    float alpha = w[tid] * r;
    g_ab[stage * 2 * HID + tid] = alpha;
    g_ab[stage * 2 * HID + HID + tid] = b[tid] - alpha * a[tid] * mean;
  }
}

// ---------------- attention scores (fused GN affine on input) --------------
__global__ __launch_bounds__(256) void k_scores(int h_id, int stage,
                                                const float* __restrict__ W1,
                                                const float* __restrict__ b1,
                                                const float* __restrict__ W2,
                                                const float* __restrict__ b2) {
  __shared__ float W1s[HID * ATTN_HID];
  __shared__ float b1s[ATTN_HID], W2s[ATTN_HID];
  __shared__ float abs_[2 * HID];
  const float* h = pick(h_id);
  const float* ab = g_ab + stage * 2 * HID;
  int tid = threadIdx.x;
  for (int f = tid; f < HID * ATTN_HID; f += 256) W1s[f] = W1[f];
  if (tid < ATTN_HID) { b1s[tid] = b1[tid]; W2s[tid] = W2[tid]; }
  if (tid < 2 * HID) abs_[tid] = ab[tid];
  __syncthreads();
  int i = blockIdx.x * 256 + tid;
  if (i >= N_NODES) return;
  float acc[ATTN_HID];
#pragma unroll
  for (int k = 0; k < ATTN_HID; ++k) acc[k] = 0.f;
  const float4* h4 = reinterpret_cast<const float4*>(h + (size_t)i * HID);
  for (int j4 = 0; j4 < HID / 4; ++j4) {
    float4 hv4 = h4[j4];
    int j = j4 * 4;
    float h0 = fmaxf(hv4.x * abs_[j]     + abs_[HID + j],     0.f);
    float h1 = fmaxf(hv4.y * abs_[j + 1] + abs_[HID + j + 1], 0.f);
    float h2 = fmaxf(hv4.z * abs_[j + 2] + abs_[HID + j + 2], 0.f);
    float h3 = fmaxf(hv4.w * abs_[j + 3] + abs_[HID + j + 3], 0.f);
#pragma unroll
    for (int k = 0; k < ATTN_HID; ++k) {
      acc[k] += h0 * W1s[j * ATTN_HID + k] + h1 * W1s[(j + 1) * ATTN_HID + k] +
                h2 * W1s[(j + 2) * ATTN_HID + k] + h3 * W1s[(j + 3) * ATTN_HID + k];
    }
  }
  float s = b2[0];
#pragma unroll
  for (int k = 0; k < ATTN_HID; ++k) s += fmaxf(acc[k] + b1s[k], 0.f) * W2s[k];
  g_scores[i] = s;
}

// ---------------- segment softmax + weighted aggregation (CSR, no atomics) -
__global__ __launch_bounds__(256) void k_spotagg(int h_id, int stage) {
  const float* __restrict__ h = pick(h_id);
  const float* ab = g_ab + stage * 2 * HID;
  int g = (blockIdx.x * 256 + threadIdx.x) >> 5;
  int lane = threadIdx.x & 31;
  if (g >= N_SPOTS) return;
  int beg = g_rps[g], end = g_rps[g + 1];
  float m = -1e30f;
  for (int i = beg + lane; i < end; i += 32) m = fmaxf(m, g_scores[g_cnode[i]]);
#pragma unroll
  for (int o = 16; o >= 1; o >>= 1) m = fmaxf(m, __shfl_xor(m, o, 32));
  float al0 = ab[lane],      be0 = ab[HID + lane];
  float al1 = ab[32 + lane], be1 = ab[HID + 32 + lane];
  float al2 = ab[64 + lane], be2 = ab[HID + 64 + lane];
  float a0 = 0.f, a1 = 0.f, a2 = 0.f, denom = 0.f;
  for (int i = beg; i < end; ++i) {
    int nd = g_cnode[i];
    float e = __expf(g_scores[nd] - m);
    denom += e;
    const float* __restrict__ hr = h + (size_t)nd * HID;
    a0 += e * fmaxf(hr[lane] * al0 + be0, 0.f);
    a1 += e * fmaxf(hr[32 + lane] * al1 + be1, 0.f);
    a2 += e * fmaxf(hr[64 + lane] * al2 + be2, 0.f);
  }
  float inv = (denom > 0.f) ? 1.f / denom : 0.f;
  g_spot[g * HID + lane]      = a0 * inv;
  g_spot[g * HID + 32 + lane] = a1 * inv;
  g_spot[g * HID + 64 + lane] = a2 * inv;
}

// ---------------- final: out = relu(gn(t3)) @ mlp_W2 + b2 ------------------
__global__ __launch_bounds__(256) void k_final(int t3_id, int stage,
                                               const float* __restrict__ W2,
                                               const float* __restrict__ b2,
                                               float* __restrict__ out) {
  __shared__ float W2s[HID * OUT_DIM];
  const float* t3 = pick(t3_id);
  const float* ab = g_ab + stage * 2 * HID;
  int tid = threadIdx.x;
  for (int f = tid; f < HID * OUT_DIM; f += 256) W2s[f] = W2[f];
  __syncthreads();
  int r = blockIdx.x * 16 + (tid >> 4);
  int c = tid & 15;
  if (r >= N_SPOTS) return;
  float acc = b2[c];
  for (int j = 0; j < HID; ++j) {
    float z = fmaxf(t3[(size_t)r * HID + j] * ab[j] + ab[HID + j], 0.f);
    acc += z * W2s[j * OUT_DIM + c];
  }
  out[r * OUT_DIM + c] = acc;
}

// ---------------------------------------------------------------------------
extern "C" void kernel_launch(void* const* d_in, const int* in_sizes, int n_in,
                              void* d_out, int out_size, void* d_ws, size_t ws_size,
                              hipStream_t stream) {
  const float* x       = (const float*)d_in[0];
  const int*   ei      = (const int*)d_in[1];
  const int*   src     = ei;
  const int*   dst     = ei + N_EDGES;
  const int*   c2s     = (const int*)d_in[2];
  const float* proj_W  = (const float*)d_in[4];
  const float* proj_b  = (const float*)d_in[5];
  const float* gn0_w   = (const float*)d_in[6];
  const float* gn0_b   = (const float*)d_in[7];
  const float* gn0_a   = (const float*)d_in[8];
  const float* gcn1_W  = (const float*)d_in[9];
  const float* gcn1_b  = (const float*)d_in[10];
  const float* gn1_w   = (const float*)d_in[11];
  const float* gn1_b   = (const float*)d_in[12];
  const float* gn1_a   = (const float*)d_in[13];
  const float* gcn2_W  = (const float*)d_in[14];
  const float* gcn2_b  = (const float*)d_in[15];
  const float* gn2_w   = (const float*)d_in[16];
  const float* gn2_b   = (const float*)d_in[17];
  const float* gn2_a   = (const float*)d_in[18];
  const float* attn_W1 = (const float*)d_in[19];
  const float* attn_b1 = (const float*)d_in[20];
  const float* attn_W2 = (const float*)d_in[21];
  const float* attn_b2 = (const float*)d_in[22];
  const float* mlp_W1  = (const float*)d_in[23];
  const float* mlp_b1  = (const float*)d_in[24];
  const float* mlp_gn_w = (const float*)d_in[25];
  const float* mlp_gn_b = (const float*)d_in[26];
  const float* mlp_gn_a = (const float*)d_in[27];
  const float* mlp_W2  = (const float*)d_in[28];
  const float* mlp_b2  = (const float*)d_in[29];
  float* out = (float*)d_out;

  const float invN = 1.f / (float)N_NODES;
  const float invS = 1.f / (float)N_SPOTS;
  const int MFB  = (N_NODES + 63) / 64;     // 782
  const int GB_S = (N_SPOTS + 63) / 64;     // 79
  const int XB   = NXCD * 96;               // 768
  const int SPB  = (N_SPOTS * 32 + 255) / 256;

  // ---- CSR build + W pre-split ----
  k_init<<<(N_NODES + 255) / 256, 256, 0, stream>>>(proj_W, gcn1_W, gcn2_W);
  k_hist<<<XB, 256, 0, stream>>>(dst, c2s);
  k_scan1<<<SCB, 256, 0, stream>>>();
  k_scan3<<<SCB, 256, 0, stream>>>();
  k_fill<<<XB, 256, 0, stream>>>(src, dst, c2s);

  // ---- stage 0: proj (MFMA bf16x3, stats fused) ----
  k_mfma<IN_DIM, false, false, true><<<MFB, 256, 0, stream>>>(x, -1, 0, 0, proj_b, 0, N_NODES);
  k_colred<<<CSB, 256, 0, stream>>>(MFB);
  k_gnreduce<<<1, 256, 0, stream>>>(0, gn0_w, gn0_b, gn0_a, invN, 0, CSB);

  // ---- GCN layer 1 ----
  k_mfma<HID, true, true, false><<<MFB, 256, 0, stream>>>(nullptr, 0, 1, 1, nullptr, 0, N_NODES);
  k_gather<<<GTHB, 256, 0, stream>>>(1, gcn1_b, 0);
  k_colred<<<CSB, 256, 0, stream>>>(GTHB);
  k_gnreduce<<<1, 256, 0, stream>>>(1, gn1_w, gn1_b, gn1_a, invN, 0, CSB);

  // ---- GCN layer 2 ----
  k_mfma<HID, true, true, false><<<MFB, 256, 0, stream>>>(nullptr, 0, 2, 2, nullptr, 1, N_NODES);
  k_gather<<<GTHB, 256, 0, stream>>>(2, gcn2_b, 1);
  k_colred<<<CSB, 256, 0, stream>>>(GTHB);
  k_gnreduce<<<1, 256, 0, stream>>>(2, gn2_w, gn2_b, gn2_a, invN, 0, CSB);

  // ---- attention + segment softmax + spot aggregation ----
  k_scores<<<(N_NODES + 255) / 256, 256, 0, stream>>>(1, 2, attn_W1, attn_b1, attn_W2, attn_b2);
  k_spotagg<<<SPB, 256, 0, stream>>>(1, 2);

  // ---- MLP head (stats fused; gnreduce reads g_gpart directly) ----
  k_gemm96<HID, false, false, true><<<GB_S, 256, 0, stream>>>(nullptr, 3, 2, mlp_W1, mlp_b1, 0, N_SPOTS);
  k_gnreduce<<<1, 256, 0, stream>>>(3, mlp_gn_w, mlp_gn_b, mlp_gn_a, invS, 1, GB_S);
  k_final<<<(N_SPOTS + 15) / 16, 256, 0, stream>>>(2, 3, mlp_W2, mlp_b2, out);
}